// Round 2
// baseline (403.073 us; speedup 1.0000x reference)
//
#include <hip/hip_runtime.h>
#include <hip/hip_bf16.h>

// ---------------------------------------------------------------------------
// MHSA + MLP block, B=4 C=128 H=W=64 (N=4096), HEADS=4 HD=32, HIDDEN=256.
// Pipeline: LN1 -> QKV gemm (emits bf16 Q,K,V; Q pre-scaled by 1/sqrt(hd)*log2e)
//           -> flash-attn (bf16 MFMA, base-2 softmax, dbuf LDS, 1 barrier/chunk)
//           -> proj+res -> LN2 -> fc1+GELU -> fc2+res.
// ws layout (floats): R0[0,2M) xln1/attnout/xln2 (reused 3x),
//   Qb/Kb/Vb bf16 at float-offsets 2M/4M/6M; HB=[2M,6M) after attn; X1=[6M,8M).
// ---------------------------------------------------------------------------

typedef __attribute__((ext_vector_type(4))) float f32x4;
typedef __attribute__((ext_vector_type(8))) short bf16x8;       // MFMA A/B frag
typedef __attribute__((ext_vector_type(8))) unsigned short ushort8;

#define C_ 128
#define N_ 4096
#define SL2E 0.25504712280087033f   // (1/sqrt(32)) * log2(e)

__device__ inline unsigned short f2bf(float f) {   // fp32 -> bf16 RNE
  unsigned int x = __float_as_uint(f);
  x += 0x7fffu + ((x >> 16) & 1u);
  return (unsigned short)(x >> 16);
}

// ---------------------------------------------------------------------------
// LayerNorm over channels. Input [B,C,N] (NCHW), output rows [B*N, C].
// ---------------------------------------------------------------------------
__global__ __launch_bounds__(256) void ln_kernel(const float* __restrict__ xin,
                                                 const float* __restrict__ gamma,
                                                 const float* __restrict__ beta,
                                                 float* __restrict__ outp) {
  __shared__ float tile[128][65];
  __shared__ float ps[4][64];
  __shared__ float pss[4][64];
  __shared__ float mu_s[64];
  __shared__ float rs_s[64];
  const int t = threadIdx.x;
  const int b = blockIdx.x >> 6;
  const int n0 = (blockIdx.x & 63) << 6;
  const float* xb = xin + (size_t)b * C_ * N_ + n0;
#pragma unroll
  for (int i = 0; i < 32; ++i) {
    int lin = i * 256 + t;
    int c = lin >> 6, p = lin & 63;
    tile[c][p] = xb[(size_t)c * N_ + p];
  }
  __syncthreads();
  {
    int p = t & 63, part = t >> 6;
    float s = 0.f, ss = 0.f;
#pragma unroll
    for (int j = 0; j < 32; ++j) {
      float v = tile[part * 32 + j][p];
      s += v; ss += v * v;
    }
    ps[part][p] = s; pss[part][p] = ss;
  }
  __syncthreads();
  if (t < 64) {
    int p = t;
    float su = ps[0][p] + ps[1][p] + ps[2][p] + ps[3][p];
    float sq = pss[0][p] + pss[1][p] + pss[2][p] + pss[3][p];
    float mu = su * (1.f / 128.f);
    float var = sq * (1.f / 128.f) - mu * mu;
    mu_s[p] = mu;
    rs_s[p] = rsqrtf(var + 1e-5f);
  }
  __syncthreads();
  float* ob = outp + (size_t)(b * N_ + n0) * C_;
#pragma unroll
  for (int i = 0; i < 32; ++i) {
    int lin = i * 256 + t;
    int p = lin >> 7, c = lin & 127;
    ob[(size_t)p * C_ + c] = (tile[c][p] - mu_s[p]) * rs_s[p] * gamma[c] + beta[c];
  }
}

// ---------------------------------------------------------------------------
// fp32 tiled GEMM core (64x64 tile, K transposed in LDS).
// ---------------------------------------------------------------------------
template <int KDIM>
__device__ inline void gemm_core(const float* __restrict__ A, const float* __restrict__ W,
                                 int row0, int col0, int t, float acc[4][4]) {
  __shared__ __align__(16) float As[64][68];   // [k][row]
  __shared__ __align__(16) float Ws[64][68];   // [k][col]
  const int r0 = (t >> 4) << 2;
  const int c0 = (t & 15) << 2;
  for (int kc = 0; kc < KDIM; kc += 64) {
    __syncthreads();
#pragma unroll
    for (int i = 0; i < 4; ++i) {
      int lin = i * 256 + t;
      int rr = lin >> 4, kk = (lin & 15) << 2;
      f32x4 av = *(const f32x4*)&A[(size_t)(row0 + rr) * KDIM + kc + kk];
      As[kk][rr] = av[0]; As[kk + 1][rr] = av[1]; As[kk + 2][rr] = av[2]; As[kk + 3][rr] = av[3];
      f32x4 wv = *(const f32x4*)&W[(size_t)(col0 + rr) * KDIM + kc + kk];
      Ws[kk][rr] = wv[0]; Ws[kk + 1][rr] = wv[1]; Ws[kk + 2][rr] = wv[2]; Ws[kk + 3][rr] = wv[3];
    }
    __syncthreads();
#pragma unroll
    for (int k = 0; k < 64; ++k) {
      f32x4 a = *(const f32x4*)&As[k][r0];
      f32x4 wv = *(const f32x4*)&Ws[k][c0];
#pragma unroll
      for (int i = 0; i < 4; ++i)
#pragma unroll
        for (int j = 0; j < 4; ++j)
          acc[i][j] = fmaf(a[i], wv[j], acc[i][j]);
    }
  }
}

// QKV gemm -> bf16 Q,K [bh][n][32], V [bh][32][n]. Q pre-scaled by SL2E.
__global__ __launch_bounds__(256) void qkv_kernel(const float* __restrict__ XLN,
                                                  const float* __restrict__ Wq,
                                                  unsigned short* __restrict__ Qb,
                                                  unsigned short* __restrict__ Kb,
                                                  unsigned short* __restrict__ Vb) {
  const int t = threadIdx.x;
  const int row0 = (blockIdx.x & 255) << 6;
  const int col0 = (blockIdx.x >> 8) << 6;
  float acc[4][4] = {};
  gemm_core<128>(XLN, Wq, row0, col0, t, acc);
  const int r0 = (t >> 4) << 2, c0 = (t & 15) << 2;
#pragma unroll
  for (int i = 0; i < 4; ++i) {
    int gp = row0 + r0 + i;
    int b = gp >> 12, n = gp & 4095;
#pragma unroll
    for (int j = 0; j < 4; ++j) {
      int o = col0 + c0 + j;
      int ch = o & 127;
      int hh = ch >> 5, d = ch & 31;
      float v = acc[i][j];
      if (o < 128) {
        Qb[((size_t)(b * 4 + hh) * 4096 + n) * 32 + d] = f2bf(v * SL2E);
      } else if (o < 256) {
        Kb[((size_t)(b * 4 + hh) * 4096 + n) * 32 + d] = f2bf(v);
      } else {
        Vb[((size_t)(b * 4 + hh) * 32 + d) * 4096 + n] = f2bf(v);
      }
    }
  }
}

// ---------------------------------------------------------------------------
// Flash attention, bf16 MFMA 16x16x32. One block = one (b,h) x 64-query tile;
// 4 waves x 16 q-rows. C/D: col=lane&15 (key/d), row=(lane>>4)*4+reg (q).
// A/B frags: row/col = lane&15, k = (lane>>4)*8 + i (b128 read).
// Double-buffered K/V LDS, next-chunk loads issued before compute (T14),
// one barrier per chunk; Ps is wave-private (no barrier).
// Logits are base-2 (Q carries 1/sqrt(hd)*log2e) -> bare v_exp_f32.
// ---------------------------------------------------------------------------
__global__ __launch_bounds__(256) void attn_kernel(const unsigned short* __restrict__ Qg,
                                                   const unsigned short* __restrict__ Kg,
                                                   const unsigned short* __restrict__ Vg,
                                                   float* __restrict__ AO) {
  __shared__ __align__(16) unsigned short Qa[64][40];
  __shared__ __align__(16) unsigned short Ks[2][64][40];
  __shared__ __align__(16) unsigned short Vt[2][32][72];
  __shared__ __align__(16) unsigned short Ps[64][72];
  const int id = blockIdx.x;                     // grid 1024
  const int bh = (id & 7) | ((id >> 9) << 3);    // xcd = bh % 8 (K/V L2-resident)
  const int qt = (id >> 3) & 63;
  const int b = bh >> 2, h = bh & 3;
  const unsigned short* Qp = Qg + ((size_t)bh * 4096 + qt * 64) * 32;
  const unsigned short* Kp = Kg + (size_t)bh * 4096 * 32;
  const unsigned short* Vp = Vg + (size_t)bh * 32 * 4096;
  const int t = threadIdx.x;
  const int lane = t & 63, w = t >> 6;
  const int l15 = lane & 15, g = lane >> 4;
  const int krow = t >> 2, kd0 = (t & 3) << 3;   // K/Q staging coords
  const int vd = t >> 3, vc0 = (t & 7) << 3;     // V staging coords

  // stage Q + chunk 0
  *(ushort8*)&Qa[krow][kd0] = *(const ushort8*)(Qp + krow * 32 + kd0);
  ushort8 kreg = *(const ushort8*)(Kp + (size_t)krow * 32 + kd0);
  ushort8 vreg = *(const ushort8*)(Vp + (size_t)vd * 4096 + vc0);
  *(ushort8*)&Ks[0][krow][kd0] = kreg;
  *(ushort8*)&Vt[0][vd][vc0] = vreg;
  __syncthreads();
  const bf16x8 aQ = *(const bf16x8*)&Qa[(w << 4) + l15][g << 3];

  const f32x4 zero = {0.f, 0.f, 0.f, 0.f};
  f32x4 opv[2]; opv[0] = zero; opv[1] = zero;
  float m_r[4] = {-1e30f, -1e30f, -1e30f, -1e30f};
  float l_r[4] = {0.f, 0.f, 0.f, 0.f};

  for (int kt = 0; kt < 64; ++kt) {
    const int cur = kt & 1;
    if (kt < 63) {  // issue next-chunk loads early; vmcnt waited at ds_write
      kreg = *(const ushort8*)(Kp + (size_t)((kt + 1) * 64 + krow) * 32 + kd0);
      vreg = *(const ushort8*)(Vp + (size_t)vd * 4096 + (kt + 1) * 64 + vc0);
    }

    f32x4 s[4];
#pragma unroll
    for (int ks = 0; ks < 4; ++ks) {   // S[16q][16key] x4, k-dim = HD = 32
      bf16x8 bK = *(const bf16x8*)&Ks[cur][(ks << 4) + l15][g << 3];
      s[ks] = __builtin_amdgcn_mfma_f32_16x16x32_bf16(aQ, bK, zero, 0, 0, 0);
    }
#pragma unroll
    for (int r = 0; r < 4; ++r) {      // online softmax (base-2) per q-row
      float v0 = s[0][r], v1 = s[1][r], v2 = s[2][r], v3 = s[3][r];
      float m0 = fmaxf(fmaxf(v0, v1), fmaxf(v2, v3));
      m0 = fmaxf(m0, __shfl_xor(m0, 1, 16));
      m0 = fmaxf(m0, __shfl_xor(m0, 2, 16));
      m0 = fmaxf(m0, __shfl_xor(m0, 4, 16));
      m0 = fmaxf(m0, __shfl_xor(m0, 8, 16));
      float mn = fmaxf(m_r[r], m0);
      float al = exp2f(m_r[r] - mn);
      m_r[r] = mn;
      float p0 = exp2f(v0 - mn), p1 = exp2f(v1 - mn);
      float p2 = exp2f(v2 - mn), p3 = exp2f(v3 - mn);
      float rs = p0 + p1 + p2 + p3;
      rs += __shfl_xor(rs, 1, 16);
      rs += __shfl_xor(rs, 2, 16);
      rs += __shfl_xor(rs, 4, 16);
      rs += __shfl_xor(rs, 8, 16);
      l_r[r] = l_r[r] * al + rs;
      opv[0][r] *= al;
      opv[1][r] *= al;
      int qrow = (w << 4) + (g << 2) + r;
      Ps[qrow][l15]      = f2bf(p0);
      Ps[qrow][16 + l15] = f2bf(p1);
      Ps[qrow][32 + l15] = f2bf(p2);
      Ps[qrow][48 + l15] = f2bf(p3);
    }
    // Ps stripe is wave-private: in-wave lgkmcnt ordering suffices, no barrier.
#pragma unroll
    for (int kb = 0; kb < 2; ++kb) {   // PV: O[16q][32d] += P[16][32k] V[32k][16d]
      bf16x8 aP = *(const bf16x8*)&Ps[(w << 4) + l15][(kb << 5) + (g << 3)];
#pragma unroll
      for (int dt = 0; dt < 2; ++dt) {
        bf16x8 bV = *(const bf16x8*)&Vt[cur][(dt << 4) + l15][(kb << 5) + (g << 3)];
        opv[dt] = __builtin_amdgcn_mfma_f32_16x16x32_bf16(aP, bV, opv[dt], 0, 0, 0);
      }
    }
    if (kt < 63) {  // write next chunk into other buffer
      *(ushort8*)&Ks[cur ^ 1][krow][kd0] = kreg;
      *(ushort8*)&Vt[cur ^ 1][vd][vc0] = vreg;
    }
    __syncthreads();
  }

  float* aob = AO + (size_t)(b * 4096 + qt * 64) * 128;
#pragma unroll
  for (int r = 0; r < 4; ++r) {
    float inv = 1.f / l_r[r];
    int qrow = (w << 4) + (g << 2) + r;
#pragma unroll
    for (int dt = 0; dt < 2; ++dt) {
      int ch = (h << 5) + (dt << 4) + l15;
      aob[(size_t)qrow * 128 + ch] = opv[dt][r] * inv;
    }
  }
}

// proj + residual: X1[b,c,n] = x[b,c,n] + AO.proj_w + proj_b
__global__ __launch_bounds__(256) void proj_kernel(const float* __restrict__ AO,
                                                   const float* __restrict__ Wp,
                                                   const float* __restrict__ bp,
                                                   const float* __restrict__ x,
                                                   float* __restrict__ X1) {
  const int t = threadIdx.x;
  const int row0 = (blockIdx.x & 255) << 6;
  const int col0 = (blockIdx.x >> 8) << 6;
  float acc[4][4] = {};
  gemm_core<128>(AO, Wp, row0, col0, t, acc);
  const int r0 = (t >> 4) << 2, c0 = (t & 15) << 2;
#pragma unroll
  for (int i = 0; i < 4; ++i) {
    int gp = row0 + r0 + i;
    int b = gp >> 12, n = gp & 4095;
#pragma unroll
    for (int j = 0; j < 4; ++j) {
      int c = col0 + c0 + j;
      size_t idx = ((size_t)(b * C_ + c) << 12) + n;
      X1[idx] = x[idx] + acc[i][j] + bp[c];
    }
  }
}

// fc1 + exact GELU -> H [16384, 256]
__global__ __launch_bounds__(256) void fc1_kernel(const float* __restrict__ XLN2,
                                                  const float* __restrict__ W1,
                                                  const float* __restrict__ b1,
                                                  float* __restrict__ Hb) {
  const int t = threadIdx.x;
  const int row0 = (blockIdx.x & 255) << 6;
  const int col0 = (blockIdx.x >> 8) << 6;
  float acc[4][4] = {};
  gemm_core<128>(XLN2, W1, row0, col0, t, acc);
  const int r0 = (t >> 4) << 2, c0 = (t & 15) << 2;
#pragma unroll
  for (int i = 0; i < 4; ++i) {
    int gp = row0 + r0 + i;
#pragma unroll
    for (int j = 0; j < 4; ++j) {
      int o = col0 + c0 + j;
      float v = acc[i][j] + b1[o];
      v = 0.5f * v * (1.f + erff(v * 0.70710678118654752f));
      Hb[(size_t)gp * 256 + o] = v;
    }
  }
}

// fc2 + residual -> out NCHW
__global__ __launch_bounds__(256) void fc2_kernel(const float* __restrict__ Hb,
                                                  const float* __restrict__ W2,
                                                  const float* __restrict__ b2,
                                                  const float* __restrict__ X1,
                                                  float* __restrict__ outp) {
  const int t = threadIdx.x;
  const int row0 = (blockIdx.x & 255) << 6;
  const int col0 = (blockIdx.x >> 8) << 6;
  float acc[4][4] = {};
  gemm_core<256>(Hb, W2, row0, col0, t, acc);
  const int r0 = (t >> 4) << 2, c0 = (t & 15) << 2;
#pragma unroll
  for (int i = 0; i < 4; ++i) {
    int gp = row0 + r0 + i;
    int b = gp >> 12, n = gp & 4095;
#pragma unroll
    for (int j = 0; j < 4; ++j) {
      int c = col0 + c0 + j;
      size_t idx = ((size_t)(b * C_ + c) << 12) + n;
      outp[idx] = X1[idx] + acc[i][j] + b2[c];
    }
  }
}

extern "C" void kernel_launch(void* const* d_in, const int* in_sizes, int n_in,
                              void* d_out, int out_size, void* d_ws, size_t ws_size,
                              hipStream_t stream) {
  (void)in_sizes; (void)n_in; (void)out_size; (void)ws_size;
  const float* x     = (const float*)d_in[0];
  const float* ln1w  = (const float*)d_in[1];
  const float* ln1b  = (const float*)d_in[2];
  const float* qkvw  = (const float*)d_in[3];
  const float* projw = (const float*)d_in[4];
  const float* projb = (const float*)d_in[5];
  const float* ln2w  = (const float*)d_in[6];
  const float* ln2b  = (const float*)d_in[7];
  const float* fc1w  = (const float*)d_in[8];
  const float* fc1b  = (const float*)d_in[9];
  const float* fc2w  = (const float*)d_in[10];
  const float* fc2b  = (const float*)d_in[11];
  float* out = (float*)d_out;
  float* ws  = (float*)d_ws;

  float* R0 = ws;                                   // 2M floats
  unsigned short* Qb = (unsigned short*)(ws + (2u << 20));
  unsigned short* Kb = (unsigned short*)(ws + (4u << 20));
  unsigned short* Vb = (unsigned short*)(ws + (6u << 20));
  float* HB = ws + (2u << 20);                      // after attn
  float* X1 = ws + (6u << 20);                      // after attn

  ln_kernel<<<dim3(256), dim3(256), 0, stream>>>(x, ln1w, ln1b, R0);
  qkv_kernel<<<dim3(1536), dim3(256), 0, stream>>>(R0, qkvw, Qb, Kb, Vb);
  attn_kernel<<<dim3(1024), dim3(256), 0, stream>>>(Qb, Kb, Vb, R0);
  proj_kernel<<<dim3(512), dim3(256), 0, stream>>>(R0, projw, projb, x, X1);
  ln_kernel<<<dim3(256), dim3(256), 0, stream>>>(X1, ln2w, ln2b, R0);
  fc1_kernel<<<dim3(1024), dim3(256), 0, stream>>>(R0, fc1w, fc1b, HB);
  fc2_kernel<<<dim3(512), dim3(256), 0, stream>>>(HB, fc2w, fc2b, X1, out);
}

// Round 5
// 310.163 us; speedup vs baseline: 1.2996x; 1.2996x over previous
//
#include <hip/hip_runtime.h>
#include <hip/hip_bf16.h>

// ---------------------------------------------------------------------------
// MHSA + MLP block, B=4 C=128 H=W=64 (N=4096), HEADS=4 HD=32, HIDDEN=256.
// Pipeline: LN1 -> QKV gemm (emits bf16 Q,K,V; Q pre-scaled by 1/sqrt(hd)*log2e)
//           -> flash-attn (swapped-operand bf16 MFMA: S^T=K.Q^T, O^T=V^T.P^T,
//              lane-local softmax, P in-register, dbuf LDS, 1 barrier/chunk)
//           -> proj+res -> LN2 -> fc1+GELU -> fc2+res.
// ws layout (floats): R0[0,2M) xln1/attnout/xln2 (reused 3x),
//   Qb/Kb/Vb bf16 at float-offsets 2M/4M/6M; HB=[2M,6M) after attn; X1=[6M,8M).
// ---------------------------------------------------------------------------

typedef __attribute__((ext_vector_type(4))) float f32x4;
typedef __attribute__((ext_vector_type(8))) short bf16x8;       // MFMA A/B frag
typedef __attribute__((ext_vector_type(8))) unsigned short ushort8;
typedef __attribute__((ext_vector_type(4))) unsigned short ushort4v;

#define C_ 128
#define N_ 4096
#define SL2E 0.25504712280087033f   // (1/sqrt(32)) * log2(e)

__device__ inline unsigned short f2bf(float f) {   // fp32 -> bf16 RNE
  unsigned int x = __float_as_uint(f);
  x += 0x7fffu + ((x >> 16) & 1u);
  return (unsigned short)(x >> 16);
}

__device__ inline unsigned int pk2(float a, float b) {  // pack 2xbf16 word
  __hip_bfloat162 h2 = __float22bfloat162_rn(make_float2(a, b));
  return *(unsigned int*)&h2;
}

// ---------------------------------------------------------------------------
// LayerNorm over channels. Input [B,C,N] (NCHW), output rows [B*N, C].
// ---------------------------------------------------------------------------
__global__ __launch_bounds__(256) void ln_kernel(const float* __restrict__ xin,
                                                 const float* __restrict__ gamma,
                                                 const float* __restrict__ beta,
                                                 float* __restrict__ outp) {
  __shared__ float tile[128][65];
  __shared__ float ps[4][64];
  __shared__ float pss[4][64];
  __shared__ float mu_s[64];
  __shared__ float rs_s[64];
  const int t = threadIdx.x;
  const int b = blockIdx.x >> 6;
  const int n0 = (blockIdx.x & 63) << 6;
  const float* xb = xin + (size_t)b * C_ * N_ + n0;
#pragma unroll
  for (int i = 0; i < 32; ++i) {
    int lin = i * 256 + t;
    int c = lin >> 6, p = lin & 63;
    tile[c][p] = xb[(size_t)c * N_ + p];
  }
  __syncthreads();
  {
    int p = t & 63, part = t >> 6;
    float s = 0.f, ss = 0.f;
#pragma unroll
    for (int j = 0; j < 32; ++j) {
      float v = tile[part * 32 + j][p];
      s += v; ss += v * v;
    }
    ps[part][p] = s; pss[part][p] = ss;
  }
  __syncthreads();
  if (t < 64) {
    int p = t;
    float su = ps[0][p] + ps[1][p] + ps[2][p] + ps[3][p];
    float sq = pss[0][p] + pss[1][p] + pss[2][p] + pss[3][p];
    float mu = su * (1.f / 128.f);
    float var = sq * (1.f / 128.f) - mu * mu;
    mu_s[p] = mu;
    rs_s[p] = rsqrtf(var + 1e-5f);
  }
  __syncthreads();
  float* ob = outp + (size_t)(b * N_ + n0) * C_;
#pragma unroll
  for (int i = 0; i < 32; ++i) {
    int lin = i * 256 + t;
    int p = lin >> 7, c = lin & 127;
    ob[(size_t)p * C_ + c] = (tile[c][p] - mu_s[p]) * rs_s[p] * gamma[c] + beta[c];
  }
}

// ---------------------------------------------------------------------------
// fp32 tiled GEMM core (64x64 tile, K transposed in LDS).
// ---------------------------------------------------------------------------
template <int KDIM>
__device__ inline void gemm_core(const float* __restrict__ A, const float* __restrict__ W,
                                 int row0, int col0, int t, float acc[4][4]) {
  __shared__ __align__(16) float As[64][68];   // [k][row]
  __shared__ __align__(16) float Ws[64][68];   // [k][col]
  const int r0 = (t >> 4) << 2;
  const int c0 = (t & 15) << 2;
  for (int kc = 0; kc < KDIM; kc += 64) {
    __syncthreads();
#pragma unroll
    for (int i = 0; i < 4; ++i) {
      int lin = i * 256 + t;
      int rr = lin >> 4, kk = (lin & 15) << 2;
      f32x4 av = *(const f32x4*)&A[(size_t)(row0 + rr) * KDIM + kc + kk];
      As[kk][rr] = av[0]; As[kk + 1][rr] = av[1]; As[kk + 2][rr] = av[2]; As[kk + 3][rr] = av[3];
      f32x4 wv = *(const f32x4*)&W[(size_t)(col0 + rr) * KDIM + kc + kk];
      Ws[kk][rr] = wv[0]; Ws[kk + 1][rr] = wv[1]; Ws[kk + 2][rr] = wv[2]; Ws[kk + 3][rr] = wv[3];
    }
    __syncthreads();
#pragma unroll
    for (int k = 0; k < 64; ++k) {
      f32x4 a = *(const f32x4*)&As[k][r0];
      f32x4 wv = *(const f32x4*)&Ws[k][c0];
#pragma unroll
      for (int i = 0; i < 4; ++i)
#pragma unroll
        for (int j = 0; j < 4; ++j)
          acc[i][j] = fmaf(a[i], wv[j], acc[i][j]);
    }
  }
}

// QKV gemm -> bf16 Q,K [bh][n][32], V [bh][32][n]. Q pre-scaled by SL2E.
__global__ __launch_bounds__(256) void qkv_kernel(const float* __restrict__ XLN,
                                                  const float* __restrict__ Wq,
                                                  unsigned short* __restrict__ Qb,
                                                  unsigned short* __restrict__ Kb,
                                                  unsigned short* __restrict__ Vb) {
  const int t = threadIdx.x;
  const int row0 = (blockIdx.x & 255) << 6;
  const int col0 = (blockIdx.x >> 8) << 6;
  float acc[4][4] = {};
  gemm_core<128>(XLN, Wq, row0, col0, t, acc);
  const int r0 = (t >> 4) << 2, c0 = (t & 15) << 2;
#pragma unroll
  for (int i = 0; i < 4; ++i) {
    int gp = row0 + r0 + i;
    int b = gp >> 12, n = gp & 4095;
#pragma unroll
    for (int j = 0; j < 4; ++j) {
      int o = col0 + c0 + j;
      int ch = o & 127;
      int hh = ch >> 5, d = ch & 31;
      float v = acc[i][j];
      if (o < 128) {
        Qb[((size_t)(b * 4 + hh) * 4096 + n) * 32 + d] = f2bf(v * SL2E);
      } else if (o < 256) {
        Kb[((size_t)(b * 4 + hh) * 4096 + n) * 32 + d] = f2bf(v);
      } else {
        Vb[((size_t)(b * 4 + hh) * 32 + d) * 4096 + n] = f2bf(v);
      }
    }
  }
}

// ---------------------------------------------------------------------------
// Flash attention, swapped-operand bf16 MFMA 16x16x32.
// One block = one (b,h) x 64-query tile; 4 waves x 16 q-rows.
// S^T = mfma(K, Q^T): lane (l15,g) holds S[key=ks*16+g*4+r][q=l15] -> softmax
// is lane-local (15 fmax + 2 shfl for max; sum deferred to end).
// PV uses the key bijection kslot(g,i=4a+r') = a*16+g*4+r' so the P B-frag is
// the lane's own registers (NO LDS for P, NO exchange). V staged with columns
// permuted (pos = g*8+a*4+r') so aV is a single b128 read.
// O^T = mfma(V^T, P^T): rescale + 1/l lane-local; output f32x4 stores.
// ---------------------------------------------------------------------------
__global__ __launch_bounds__(256) void attn_kernel(const unsigned short* __restrict__ Qg,
                                                   const unsigned short* __restrict__ Kg,
                                                   const unsigned short* __restrict__ Vg,
                                                   float* __restrict__ AO) {
  __shared__ __align__(16) unsigned short Qa[64][40];
  __shared__ __align__(16) unsigned short Ks[2][64][40];
  __shared__ __align__(16) unsigned short Vt[2][32][72];
  const int id = blockIdx.x;                     // grid 1024
  const int bh = (id & 7) | ((id >> 9) << 3);    // xcd = bh % 8 (K/V L2-resident)
  const int qt = (id >> 3) & 63;
  const int b = bh >> 2, h = bh & 3;
  const unsigned short* Qp = Qg + ((size_t)bh * 4096 + qt * 64) * 32;
  const unsigned short* Kp = Kg + (size_t)bh * 4096 * 32;
  const unsigned short* Vp = Vg + (size_t)bh * 32 * 4096;
  const int t = threadIdx.x;
  const int lane = t & 63, w = t >> 6;
  const int l15 = lane & 15, g = lane >> 4;
  const int krow = t >> 2, kd0 = (t & 3) << 3;   // K/Q staging coords
  const int vd = t >> 3, vc = t & 7;             // V staging: row, key-octet
  // permuted V column base: octet c covers keys 8c..8c+7 ->
  // pos = (c>>2)*32 + (c&1)*16 + ((c&3)>>1)*4, split m=0..3 / m=4..7 (+8)
  const int vpos = ((vc >> 2) << 5) + ((vc & 1) << 4) + (((vc & 3) >> 1) << 2);

  // stage Q + chunk 0
  *(ushort8*)&Qa[krow][kd0] = *(const ushort8*)(Qp + krow * 32 + kd0);
  ushort8 kreg = *(const ushort8*)(Kp + (size_t)krow * 32 + kd0);
  ushort8 vreg = *(const ushort8*)(Vp + (size_t)vd * 4096 + (vc << 3));
  *(ushort8*)&Ks[0][krow][kd0] = kreg;
  {
    ushort4v lo = {vreg[0], vreg[1], vreg[2], vreg[3]};
    ushort4v hi = {vreg[4], vreg[5], vreg[6], vreg[7]};
    *(ushort4v*)&Vt[0][vd][vpos] = lo;
    *(ushort4v*)&Vt[0][vd][vpos + 8] = hi;
  }
  __syncthreads();
  const bf16x8 aQ = *(const bf16x8*)&Qa[(w << 4) + l15][g << 3];

  const f32x4 zero = {0.f, 0.f, 0.f, 0.f};
  f32x4 opv[2]; opv[0] = zero; opv[1] = zero;
  float m_r = -1e30f, l_r = 0.f;

  for (int kt = 0; kt < 64; ++kt) {
    const int cur = kt & 1;
    if (kt < 63) {  // issue next-chunk loads early (hide under MFMA+softmax)
      kreg = *(const ushort8*)(Kp + (size_t)((kt + 1) * 64 + krow) * 32 + kd0);
      vreg = *(const ushort8*)(Vp + (size_t)vd * 4096 + (kt + 1) * 64 + (vc << 3));
    }

    f32x4 s[4];
#pragma unroll
    for (int ks = 0; ks < 4; ++ks) {   // S^T[16key][16q], k-dim = HD = 32
      bf16x8 bK = *(const bf16x8*)&Ks[cur][(ks << 4) + l15][g << 3];
      s[ks] = __builtin_amdgcn_mfma_f32_16x16x32_bf16(bK, aQ, zero, 0, 0, 0);
    }

    // lane-local online softmax (base-2 logits), q = l15
    float m0 = fmaxf(
        fmaxf(fmaxf(fmaxf(s[0][0], s[0][1]), fmaxf(s[0][2], s[0][3])),
              fmaxf(fmaxf(s[1][0], s[1][1]), fmaxf(s[1][2], s[1][3]))),
        fmaxf(fmaxf(fmaxf(s[2][0], s[2][1]), fmaxf(s[2][2], s[2][3])),
              fmaxf(fmaxf(s[3][0], s[3][1]), fmaxf(s[3][2], s[3][3]))));
    m0 = fmaxf(m0, __shfl_xor(m0, 16));
    m0 = fmaxf(m0, __shfl_xor(m0, 32));
    float mn = fmaxf(m_r, m0);
    float al = exp2f(m_r - mn);
    m_r = mn;
    float p[4][4];
    float ls = 0.f;
#pragma unroll
    for (int ks = 0; ks < 4; ++ks)
#pragma unroll
      for (int r = 0; r < 4; ++r) {
        p[ks][r] = exp2f(s[ks][r] - mn);
        ls += p[ks][r];
      }
    l_r = l_r * al + ls;              // per-lane partial sum (own 16 keys)
    opv[0] *= al;
    opv[1] *= al;

    // pack P into PV B-frags: frag pi covers ks=2pi,2pi+1;
    // word order (i=4a+r'): [a=0: r'01, r'23][a=1: r'01, r'23]
#pragma unroll
    for (int pi = 0; pi < 2; ++pi) {
      union { unsigned int u[4]; bf16x8 v; } bP;
      bP.u[0] = pk2(p[2 * pi][0], p[2 * pi][1]);
      bP.u[1] = pk2(p[2 * pi][2], p[2 * pi][3]);
      bP.u[2] = pk2(p[2 * pi + 1][0], p[2 * pi + 1][1]);
      bP.u[3] = pk2(p[2 * pi + 1][2], p[2 * pi + 1][3]);
#pragma unroll
      for (int dt = 0; dt < 2; ++dt) {  // O^T[16d][16q] += V^T P^T
        bf16x8 aV = *(const bf16x8*)&Vt[cur][(dt << 4) + l15][(pi << 5) + (g << 3)];
        opv[dt] = __builtin_amdgcn_mfma_f32_16x16x32_bf16(aV, bP.v, opv[dt], 0, 0, 0);
      }
    }

    if (kt < 63) {  // write next chunk into other buffer
      *(ushort8*)&Ks[cur ^ 1][krow][kd0] = kreg;
      ushort4v lo = {vreg[0], vreg[1], vreg[2], vreg[3]};
      ushort4v hi = {vreg[4], vreg[5], vreg[6], vreg[7]};
      *(ushort4v*)&Vt[cur ^ 1][vd][vpos] = lo;
      *(ushort4v*)&Vt[cur ^ 1][vd][vpos + 8] = hi;
    }
    __syncthreads();
  }

  // finalize: cross-g sum of l, lane-local normalize, vector store
  l_r += __shfl_xor(l_r, 16);
  l_r += __shfl_xor(l_r, 32);
  float inv = 1.f / l_r;
  const int n = qt * 64 + (w << 4) + l15;
  float* aob = AO + (size_t)(b * 4096 + n) * 128 + (h << 5);
#pragma unroll
  for (int dt = 0; dt < 2; ++dt) {
    f32x4 o = opv[dt] * inv;
    *(f32x4*)&aob[(dt << 4) + (g << 2)] = o;
  }
}

// proj + residual: X1[b,c,n] = x[b,c,n] + AO.proj_w + proj_b
__global__ __launch_bounds__(256) void proj_kernel(const float* __restrict__ AO,
                                                   const float* __restrict__ Wp,
                                                   const float* __restrict__ bp,
                                                   const float* __restrict__ x,
                                                   float* __restrict__ X1) {
  const int t = threadIdx.x;
  const int row0 = (blockIdx.x & 255) << 6;
  const int col0 = (blockIdx.x >> 8) << 6;
  float acc[4][4] = {};
  gemm_core<128>(AO, Wp, row0, col0, t, acc);
  const int r0 = (t >> 4) << 2, c0 = (t & 15) << 2;
#pragma unroll
  for (int i = 0; i < 4; ++i) {
    int gp = row0 + r0 + i;
    int b = gp >> 12, n = gp & 4095;
#pragma unroll
    for (int j = 0; j < 4; ++j) {
      int c = col0 + c0 + j;
      size_t idx = ((size_t)(b * C_ + c) << 12) + n;
      X1[idx] = x[idx] + acc[i][j] + bp[c];
    }
  }
}

// fc1 + exact GELU -> H [16384, 256]
__global__ __launch_bounds__(256) void fc1_kernel(const float* __restrict__ XLN2,
                                                  const float* __restrict__ W1,
                                                  const float* __restrict__ b1,
                                                  float* __restrict__ Hb) {
  const int t = threadIdx.x;
  const int row0 = (blockIdx.x & 255) << 6;
  const int col0 = (blockIdx.x >> 8) << 6;
  float acc[4][4] = {};
  gemm_core<128>(XLN2, W1, row0, col0, t, acc);
  const int r0 = (t >> 4) << 2, c0 = (t & 15) << 2;
#pragma unroll
  for (int i = 0; i < 4; ++i) {
    int gp = row0 + r0 + i;
#pragma unroll
    for (int j = 0; j < 4; ++j) {
      int o = col0 + c0 + j;
      float v = acc[i][j] + b1[o];
      v = 0.5f * v * (1.f + erff(v * 0.70710678118654752f));
      Hb[(size_t)gp * 256 + o] = v;
    }
  }
}

// fc2 + residual -> out NCHW
__global__ __launch_bounds__(256) void fc2_kernel(const float* __restrict__ Hb,
                                                  const float* __restrict__ W2,
                                                  const float* __restrict__ b2,
                                                  const float* __restrict__ X1,
                                                  float* __restrict__ outp) {
  const int t = threadIdx.x;
  const int row0 = (blockIdx.x & 255) << 6;
  const int col0 = (blockIdx.x >> 8) << 6;
  float acc[4][4] = {};
  gemm_core<256>(Hb, W2, row0, col0, t, acc);
  const int r0 = (t >> 4) << 2, c0 = (t & 15) << 2;
#pragma unroll
  for (int i = 0; i < 4; ++i) {
    int gp = row0 + r0 + i;
    int b = gp >> 12, n = gp & 4095;
#pragma unroll
    for (int j = 0; j < 4; ++j) {
      int c = col0 + c0 + j;
      size_t idx = ((size_t)(b * C_ + c) << 12) + n;
      outp[idx] = X1[idx] + acc[i][j] + b2[c];
    }
  }
}

extern "C" void kernel_launch(void* const* d_in, const int* in_sizes, int n_in,
                              void* d_out, int out_size, void* d_ws, size_t ws_size,
                              hipStream_t stream) {
  (void)in_sizes; (void)n_in; (void)out_size; (void)ws_size;
  const float* x     = (const float*)d_in[0];
  const float* ln1w  = (const float*)d_in[1];
  const float* ln1b  = (const float*)d_in[2];
  const float* qkvw  = (const float*)d_in[3];
  const float* projw = (const float*)d_in[4];
  const float* projb = (const float*)d_in[5];
  const float* ln2w  = (const float*)d_in[6];
  const float* ln2b  = (const float*)d_in[7];
  const float* fc1w  = (const float*)d_in[8];
  const float* fc1b  = (const float*)d_in[9];
  const float* fc2w  = (const float*)d_in[10];
  const float* fc2b  = (const float*)d_in[11];
  float* out = (float*)d_out;
  float* ws  = (float*)d_ws;

  float* R0 = ws;                                   // 2M floats
  unsigned short* Qb = (unsigned short*)(ws + (2u << 20));
  unsigned short* Kb = (unsigned short*)(ws + (4u << 20));
  unsigned short* Vb = (unsigned short*)(ws + (6u << 20));
  float* HB = ws + (2u << 20);                      // after attn
  float* X1 = ws + (6u << 20);                      // after attn

  ln_kernel<<<dim3(256), dim3(256), 0, stream>>>(x, ln1w, ln1b, R0);
  qkv_kernel<<<dim3(1536), dim3(256), 0, stream>>>(R0, qkvw, Qb, Kb, Vb);
  attn_kernel<<<dim3(1024), dim3(256), 0, stream>>>(Qb, Kb, Vb, R0);
  proj_kernel<<<dim3(512), dim3(256), 0, stream>>>(R0, projw, projb, x, X1);
  ln_kernel<<<dim3(256), dim3(256), 0, stream>>>(X1, ln2w, ln2b, R0);
  fc1_kernel<<<dim3(1024), dim3(256), 0, stream>>>(R0, fc1w, fc1b, HB);
  fc2_kernel<<<dim3(512), dim3(256), 0, stream>>>(HB, fc2w, fc2b, X1, out);
}

// Round 7
// 247.080 us; speedup vs baseline: 1.6313x; 1.2553x over previous
//
#include <hip/hip_runtime.h>
#include <hip/hip_bf16.h>

// ---------------------------------------------------------------------------
// MHSA + MLP block, B=4 C=128 H=W=64 (N=4096), HEADS=4 HD=32, HIDDEN=256.
// All GEMMs bf16 MFMA (16x16x32), activations bf16, residual spine fp32.
// Pipeline: wconv -> LN1(bf16) -> QKV mfma -> flash-attn (swapped-operand,
//           lane-local softmax, P in-register) -> proj mfma (+x, fp32)
//           -> LN2(bf16) -> fc1 mfma (+GELU) -> fc2 mfma (+X1) -> out.
// ws layout (bytes): WB bf16 weights [0,1M), XLN/AO bf16 [1M,5M),
//   Qb/XLN2 [5M,9M), Kb [9M,13M), Vb [13M,17M), H bf16 [9M,17M) after attn,
//   X1 f32 [17M,25M).  Total 25 MB.
// ---------------------------------------------------------------------------

typedef __attribute__((ext_vector_type(4))) float f32x4;
typedef __attribute__((ext_vector_type(8))) short bf16x8;       // MFMA A/B frag
typedef __attribute__((ext_vector_type(8))) unsigned short ushort8;
typedef __attribute__((ext_vector_type(4))) unsigned short ushort4v;

#define C_ 128
#define N_ 4096
#define SL2E 0.25504712280087033f   // (1/sqrt(32)) * log2(e)

__device__ inline unsigned short f2bf(float f) {   // fp32 -> bf16 RNE
  unsigned int x = __float_as_uint(f);
  x += 0x7fffu + ((x >> 16) & 1u);
  return (unsigned short)(x >> 16);
}

__device__ inline unsigned int pk2(float a, float b) {  // pack 2xbf16 word
  __hip_bfloat162 h2 = __float22bfloat162_rn(make_float2(a, b));
  return *(unsigned int*)&h2;
}

// Weight conversion: qkv_w(49152) | proj_w(16384) | fc1_w(32768) | fc2_w(32768)
__global__ __launch_bounds__(256) void wconv_kernel(const float* __restrict__ qkvw,
                                                    const float* __restrict__ projw,
                                                    const float* __restrict__ fc1w,
                                                    const float* __restrict__ fc2w,
                                                    unsigned short* __restrict__ WB) {
  int i = blockIdx.x * 256 + threadIdx.x;       // grid 512 -> 131072
  float v;
  if (i < 49152) v = qkvw[i];
  else if (i < 65536) v = projw[i - 49152];
  else if (i < 98304) v = fc1w[i - 65536];
  else v = fc2w[i - 98304];
  WB[i] = f2bf(v);
}

// ---------------------------------------------------------------------------
// LayerNorm over channels. Input [B,C,N] (NCHW) f32, output rows [B*N, C] bf16.
// ---------------------------------------------------------------------------
__global__ __launch_bounds__(256) void ln_kernel(const float* __restrict__ xin,
                                                 const float* __restrict__ gamma,
                                                 const float* __restrict__ beta,
                                                 unsigned short* __restrict__ outp) {
  __shared__ float tile[128][65];
  __shared__ float ps[4][64];
  __shared__ float pss[4][64];
  __shared__ float mu_s[64];
  __shared__ float rs_s[64];
  const int t = threadIdx.x;
  const int b = blockIdx.x >> 6;
  const int n0 = (blockIdx.x & 63) << 6;
  const float* xb = xin + (size_t)b * C_ * N_ + n0;
#pragma unroll
  for (int i = 0; i < 32; ++i) {
    int lin = i * 256 + t;
    int c = lin >> 6, p = lin & 63;
    tile[c][p] = xb[(size_t)c * N_ + p];
  }
  __syncthreads();
  {
    int p = t & 63, part = t >> 6;
    float s = 0.f, ss = 0.f;
#pragma unroll
    for (int j = 0; j < 32; ++j) {
      float v = tile[part * 32 + j][p];
      s += v; ss += v * v;
    }
    ps[part][p] = s; pss[part][p] = ss;
  }
  __syncthreads();
  if (t < 64) {
    int p = t;
    float su = ps[0][p] + ps[1][p] + ps[2][p] + ps[3][p];
    float sq = pss[0][p] + pss[1][p] + pss[2][p] + pss[3][p];
    float mu = su * (1.f / 128.f);
    float var = sq * (1.f / 128.f) - mu * mu;
    mu_s[p] = mu;
    rs_s[p] = rsqrtf(var + 1e-5f);
  }
  __syncthreads();
  unsigned short* ob = outp + (size_t)(b * N_ + n0) * C_;
#pragma unroll
  for (int i = 0; i < 16; ++i) {            // 64 pos x 128 ch, 2 ch per thread
    int lin = i * 256 + t;
    int p = lin >> 6, c2 = (lin & 63) << 1;
    float mu = mu_s[p], rs = rs_s[p];
    float a = (tile[c2][p] - mu) * rs * gamma[c2] + beta[c2];
    float d = (tile[c2 + 1][p] - mu) * rs * gamma[c2 + 1] + beta[c2 + 1];
    *(unsigned int*)&ob[(size_t)p * C_ + c2] = pk2(a, d);
  }
}

// ---------------------------------------------------------------------------
// bf16 MFMA GEMM core. A [M,KD] bf16 row-major, W [O,KD] bf16 row-major.
// Block: 256 thr = 4 waves; tile 128 rows x 64 cols; wave w owns 32 rows.
// LDS XOR-swizzle (16B-chunk ^ (row&7)) -> A/B b128 reads 2-way max (free).
// acc[mi][nj]: D col=lane&15 (out ch), row=(lane>>4)*4+r (activation row).
// ---------------------------------------------------------------------------
template <int KD>
__device__ inline void mfma_core(const unsigned short* __restrict__ A,
                                 const unsigned short* __restrict__ W,
                                 int row0, int col0, f32x4 acc[2][4]) {
  __shared__ __align__(16) unsigned short As[128][128];
  __shared__ __align__(16) unsigned short Ws[64][128];
  const int t = threadIdx.x;
  const int w = t >> 6, lane = t & 63;
  const int l15 = lane & 15, g = lane >> 4;
  const int srow = t >> 4, schunk = t & 15;    // staging: 16 thr cover one row
#pragma unroll
  for (int kt = 0; kt < KD / 128; ++kt) {
    __syncthreads();
#pragma unroll
    for (int i = 0; i < 8; ++i) {              // A tile 128x128
      int row = i * 16 + srow;
      int c = schunk ^ (row & 7);
      *(ushort8*)&As[row][c * 8] =
          *(const ushort8*)&A[(size_t)(row0 + row) * KD + kt * 128 + schunk * 8];
    }
#pragma unroll
    for (int i = 0; i < 4; ++i) {              // W tile 64x128
      int row = i * 16 + srow;
      int c = schunk ^ (row & 7);
      *(ushort8*)&Ws[row][c * 8] =
          *(const ushort8*)&W[(size_t)(col0 + row) * KD + kt * 128 + schunk * 8];
    }
    __syncthreads();
#pragma unroll
    for (int kk = 0; kk < 4; ++kk) {
      bf16x8 aA[2], bW[4];
#pragma unroll
      for (int mi = 0; mi < 2; ++mi) {
        int mrow = (w << 5) + (mi << 4) + l15;
        int c = (kk * 4 + g) ^ (mrow & 7);
        aA[mi] = *(const bf16x8*)&As[mrow][c * 8];
      }
#pragma unroll
      for (int nj = 0; nj < 4; ++nj) {
        int wrow = (nj << 4) + l15;
        int c = (kk * 4 + g) ^ (wrow & 7);
        bW[nj] = *(const bf16x8*)&Ws[wrow][c * 8];
      }
#pragma unroll
      for (int mi = 0; mi < 2; ++mi)
#pragma unroll
        for (int nj = 0; nj < 4; ++nj)
          acc[mi][nj] = __builtin_amdgcn_mfma_f32_16x16x32_bf16(aA[mi], bW[nj],
                                                                acc[mi][nj], 0, 0, 0);
    }
  }
}

// QKV: XLN [16384,128] x WB[384,128] -> bf16 Q,K [bh][n][32], V [bh][32][n].
__global__ __launch_bounds__(256) void qkv_kernel(const unsigned short* __restrict__ XLN,
                                                  const unsigned short* __restrict__ Wq,
                                                  unsigned short* __restrict__ Qb,
                                                  unsigned short* __restrict__ Kb,
                                                  unsigned short* __restrict__ Vb) {
  const int row0 = blockIdx.x << 7, col0 = blockIdx.y << 6;
  f32x4 acc[2][4] = {};
  mfma_core<128>(XLN, Wq, row0, col0, acc);
  const int t = threadIdx.x, w = t >> 6, lane = t & 63;
  const int l15 = lane & 15, g = lane >> 4;
#pragma unroll
  for (int mi = 0; mi < 2; ++mi) {
    int grow = row0 + (w << 5) + (mi << 4) + (g << 2);
    int b = grow >> 12, n0 = grow & 4095;
#pragma unroll
    for (int nj = 0; nj < 4; ++nj) {
      int o = col0 + (nj << 4) + l15;
      int ch = o & 127, hh = ch >> 5, d = ch & 31;
      f32x4 a = acc[mi][nj];
      if (o < 128) {
        size_t base = ((size_t)(b * 4 + hh) * 4096 + n0) * 32 + d;
#pragma unroll
        for (int r = 0; r < 4; ++r) Qb[base + (size_t)r * 32] = f2bf(a[r] * SL2E);
      } else if (o < 256) {
        size_t base = ((size_t)(b * 4 + hh) * 4096 + n0) * 32 + d;
#pragma unroll
        for (int r = 0; r < 4; ++r) Kb[base + (size_t)r * 32] = f2bf(a[r]);
      } else {
        ushort4v u = {f2bf(a[0]), f2bf(a[1]), f2bf(a[2]), f2bf(a[3])};
        *(ushort4v*)&Vb[((size_t)(b * 4 + hh) * 32 + d) * 4096 + n0] = u;
      }
    }
  }
}

// ---------------------------------------------------------------------------
// Flash attention, swapped-operand bf16 MFMA (unchanged core; bf16 AO out).
// ---------------------------------------------------------------------------
__global__ __launch_bounds__(256) void attn_kernel(const unsigned short* __restrict__ Qg,
                                                   const unsigned short* __restrict__ Kg,
                                                   const unsigned short* __restrict__ Vg,
                                                   unsigned short* __restrict__ AO) {
  __shared__ __align__(16) unsigned short Qa[64][40];
  __shared__ __align__(16) unsigned short Ks[2][64][40];
  __shared__ __align__(16) unsigned short Vt[2][32][72];
  const int id = blockIdx.x;                     // grid 1024
  const int bh = (id & 7) | ((id >> 9) << 3);    // xcd = bh % 8 (K/V L2-resident)
  const int qt = (id >> 3) & 63;
  const int b = bh >> 2, h = bh & 3;
  const unsigned short* Qp = Qg + ((size_t)bh * 4096 + qt * 64) * 32;
  const unsigned short* Kp = Kg + (size_t)bh * 4096 * 32;
  const unsigned short* Vp = Vg + (size_t)bh * 32 * 4096;
  const int t = threadIdx.x;
  const int lane = t & 63, w = t >> 6;
  const int l15 = lane & 15, g = lane >> 4;
  const int krow = t >> 2, kd0 = (t & 3) << 3;   // K/Q staging coords
  const int vd = t >> 3, vc = t & 7;             // V staging: row, key-octet
  const int vpos = ((vc >> 2) << 5) + ((vc & 1) << 4) + (((vc & 3) >> 1) << 2);

  *(ushort8*)&Qa[krow][kd0] = *(const ushort8*)(Qp + krow * 32 + kd0);
  ushort8 kreg = *(const ushort8*)(Kp + (size_t)krow * 32 + kd0);
  ushort8 vreg = *(const ushort8*)(Vp + (size_t)vd * 4096 + (vc << 3));
  *(ushort8*)&Ks[0][krow][kd0] = kreg;
  {
    ushort4v lo = {vreg[0], vreg[1], vreg[2], vreg[3]};
    ushort4v hi = {vreg[4], vreg[5], vreg[6], vreg[7]};
    *(ushort4v*)&Vt[0][vd][vpos] = lo;
    *(ushort4v*)&Vt[0][vd][vpos + 8] = hi;
  }
  __syncthreads();
  const bf16x8 aQ = *(const bf16x8*)&Qa[(w << 4) + l15][g << 3];

  const f32x4 zero = {0.f, 0.f, 0.f, 0.f};
  f32x4 opv[2]; opv[0] = zero; opv[1] = zero;
  float m_r = -1e30f, l_r = 0.f;

  for (int kt = 0; kt < 64; ++kt) {
    const int cur = kt & 1;
    if (kt < 63) {
      kreg = *(const ushort8*)(Kp + (size_t)((kt + 1) * 64 + krow) * 32 + kd0);
      vreg = *(const ushort8*)(Vp + (size_t)vd * 4096 + (kt + 1) * 64 + (vc << 3));
    }

    f32x4 s[4];
#pragma unroll
    for (int ks = 0; ks < 4; ++ks) {
      bf16x8 bK = *(const bf16x8*)&Ks[cur][(ks << 4) + l15][g << 3];
      s[ks] = __builtin_amdgcn_mfma_f32_16x16x32_bf16(bK, aQ, zero, 0, 0, 0);
    }

    float m0 = fmaxf(
        fmaxf(fmaxf(fmaxf(s[0][0], s[0][1]), fmaxf(s[0][2], s[0][3])),
              fmaxf(fmaxf(s[1][0], s[1][1]), fmaxf(s[1][2], s[1][3]))),
        fmaxf(fmaxf(fmaxf(s[2][0], s[2][1]), fmaxf(s[2][2], s[2][3])),
              fmaxf(fmaxf(s[3][0], s[3][1]), fmaxf(s[3][2], s[3][3]))));
    m0 = fmaxf(m0, __shfl_xor(m0, 16));
    m0 = fmaxf(m0, __shfl_xor(m0, 32));
    float mn = fmaxf(m_r, m0);
    float al = exp2f(m_r - mn);
    m_r = mn;
    float p[4][4];
    float ls = 0.f;
#pragma unroll
    for (int ks = 0; ks < 4; ++ks)
#pragma unroll
      for (int r = 0; r < 4; ++r) {
        p[ks][r] = exp2f(s[ks][r] - mn);
        ls += p[ks][r];
      }
    l_r = l_r * al + ls;
    opv[0] *= al;
    opv[1] *= al;

#pragma unroll
    for (int pi = 0; pi < 2; ++pi) {
      union { unsigned int u[4]; bf16x8 v; } bP;
      bP.u[0] = pk2(p[2 * pi][0], p[2 * pi][1]);
      bP.u[1] = pk2(p[2 * pi][2], p[2 * pi][3]);
      bP.u[2] = pk2(p[2 * pi + 1][0], p[2 * pi + 1][1]);
      bP.u[3] = pk2(p[2 * pi + 1][2], p[2 * pi + 1][3]);
#pragma unroll
      for (int dt = 0; dt < 2; ++dt) {
        bf16x8 aV = *(const bf16x8*)&Vt[cur][(dt << 4) + l15][(pi << 5) + (g << 3)];
        opv[dt] = __builtin_amdgcn_mfma_f32_16x16x32_bf16(aV, bP.v, opv[dt], 0, 0, 0);
      }
    }

    if (kt < 63) {
      *(ushort8*)&Ks[cur ^ 1][krow][kd0] = kreg;
      ushort4v lo = {vreg[0], vreg[1], vreg[2], vreg[3]};
      ushort4v hi = {vreg[4], vreg[5], vreg[6], vreg[7]};
      *(ushort4v*)&Vt[cur ^ 1][vd][vpos] = lo;
      *(ushort4v*)&Vt[cur ^ 1][vd][vpos + 8] = hi;
    }
    __syncthreads();
  }

  l_r += __shfl_xor(l_r, 16);
  l_r += __shfl_xor(l_r, 32);
  float inv = 1.f / l_r;
  const int n = qt * 64 + (w << 4) + l15;
  unsigned short* aob = AO + (size_t)(b * 4096 + n) * 128 + (h << 5);
#pragma unroll
  for (int dt = 0; dt < 2; ++dt) {
    f32x4 o = opv[dt] * inv;
    ushort4v u = {f2bf(o[0]), f2bf(o[1]), f2bf(o[2]), f2bf(o[3])};
    *(ushort4v*)&aob[(dt << 4) + (g << 2)] = u;
  }
}

// proj + residual: X1[b,c,n] (f32) = x + AO.proj_w + proj_b
__global__ __launch_bounds__(256) void proj_kernel(const unsigned short* __restrict__ AO,
                                                   const unsigned short* __restrict__ Wp,
                                                   const float* __restrict__ bp,
                                                   const float* __restrict__ x,
                                                   float* __restrict__ X1) {
  const int row0 = blockIdx.x << 7, col0 = blockIdx.y << 6;
  f32x4 acc[2][4] = {};
  mfma_core<128>(AO, Wp, row0, col0, acc);
  const int t = threadIdx.x, w = t >> 6, lane = t & 63;
  const int l15 = lane & 15, g = lane >> 4;
#pragma unroll
  for (int mi = 0; mi < 2; ++mi) {
    int grow = row0 + (w << 5) + (mi << 4) + (g << 2);
    int b = grow >> 12, n0 = grow & 4095;
#pragma unroll
    for (int nj = 0; nj < 4; ++nj) {
      int c = col0 + (nj << 4) + l15;
      size_t idx = ((size_t)(b * C_ + c) << 12) + n0;
      f32x4 xv = *(const f32x4*)&x[idx];
      f32x4 r = xv + acc[mi][nj] + bp[c];
      *(f32x4*)&X1[idx] = r;
    }
  }
}

// fc1 + exact GELU -> H bf16 [16384, 256]
__global__ __launch_bounds__(256) void fc1_kernel(const unsigned short* __restrict__ XLN2,
                                                  const unsigned short* __restrict__ W1,
                                                  const float* __restrict__ b1,
                                                  unsigned short* __restrict__ Hb) {
  const int row0 = blockIdx.x << 7, col0 = blockIdx.y << 6;
  f32x4 acc[2][4] = {};
  mfma_core<128>(XLN2, W1, row0, col0, acc);
  const int t = threadIdx.x, w = t >> 6, lane = t & 63;
  const int l15 = lane & 15, g = lane >> 4;
#pragma unroll
  for (int mi = 0; mi < 2; ++mi) {
    int grow = row0 + (w << 5) + (mi << 4) + (g << 2);
#pragma unroll
    for (int nj = 0; nj < 4; ++nj) {
      int o = col0 + (nj << 4) + l15;
      float bb = b1[o];
#pragma unroll
      for (int r = 0; r < 4; ++r) {
        float v = acc[mi][nj][r] + bb;
        v = 0.5f * v * (1.f + erff(v * 0.70710678118654752f));
        Hb[(size_t)(grow + r) * 256 + o] = f2bf(v);
      }
    }
  }
}

// fc2 + residual -> out f32 NCHW
__global__ __launch_bounds__(256) void fc2_kernel(const unsigned short* __restrict__ Hb,
                                                  const unsigned short* __restrict__ W2,
                                                  const float* __restrict__ b2,
                                                  const float* __restrict__ X1,
                                                  float* __restrict__ outp) {
  const int row0 = blockIdx.x << 7, col0 = blockIdx.y << 6;
  f32x4 acc[2][4] = {};
  mfma_core<256>(Hb, W2, row0, col0, acc);
  const int t = threadIdx.x, w = t >> 6, lane = t & 63;
  const int l15 = lane & 15, g = lane >> 4;
#pragma unroll
  for (int mi = 0; mi < 2; ++mi) {
    int grow = row0 + (w << 5) + (mi << 4) + (g << 2);
    int b = grow >> 12, n0 = grow & 4095;
#pragma unroll
    for (int nj = 0; nj < 4; ++nj) {
      int c = col0 + (nj << 4) + l15;
      size_t idx = ((size_t)(b * C_ + c) << 12) + n0;
      f32x4 xv = *(const f32x4*)&X1[idx];
      f32x4 r = xv + acc[mi][nj] + b2[c];
      *(f32x4*)&outp[idx] = r;
    }
  }
}

extern "C" void kernel_launch(void* const* d_in, const int* in_sizes, int n_in,
                              void* d_out, int out_size, void* d_ws, size_t ws_size,
                              hipStream_t stream) {
  (void)in_sizes; (void)n_in; (void)out_size; (void)ws_size;
  const float* x     = (const float*)d_in[0];
  const float* ln1w  = (const float*)d_in[1];
  const float* ln1b  = (const float*)d_in[2];
  const float* qkvw  = (const float*)d_in[3];
  const float* projw = (const float*)d_in[4];
  const float* projb = (const float*)d_in[5];
  const float* ln2w  = (const float*)d_in[6];
  const float* ln2b  = (const float*)d_in[7];
  const float* fc1w  = (const float*)d_in[8];
  const float* fc1b  = (const float*)d_in[9];
  const float* fc2w  = (const float*)d_in[10];
  const float* fc2b  = (const float*)d_in[11];
  float* out = (float*)d_out;
  char* ws8 = (char*)d_ws;

  const size_t MB = 1u << 20;
  unsigned short* WB   = (unsigned short*)(ws8);            // 256 KB used
  unsigned short* XLN  = (unsigned short*)(ws8 + 1 * MB);   // 4 MB, reused as AO
  unsigned short* Qb   = (unsigned short*)(ws8 + 5 * MB);   // 4 MB, reused as XLN2
  unsigned short* Kb   = (unsigned short*)(ws8 + 9 * MB);   // 4 MB
  unsigned short* Vb   = (unsigned short*)(ws8 + 13 * MB);  // 4 MB
  unsigned short* AObf = XLN;                               // after qkv
  unsigned short* XLN2 = Qb;                                // after attn
  unsigned short* HB   = Kb;                                // 8 MB (K+V), after attn
  float*          X1   = (float*)(ws8 + 17 * MB);           // 8 MB
  const unsigned short* Wqkv = WB;
  const unsigned short* Wproj = WB + 49152;
  const unsigned short* Wfc1 = WB + 65536;
  const unsigned short* Wfc2 = WB + 98304;

  wconv_kernel<<<dim3(512), dim3(256), 0, stream>>>(qkvw, projw, fc1w, fc2w, WB);
  ln_kernel<<<dim3(256), dim3(256), 0, stream>>>(x, ln1w, ln1b, XLN);
  qkv_kernel<<<dim3(128, 6), dim3(256), 0, stream>>>(XLN, Wqkv, Qb, Kb, Vb);
  attn_kernel<<<dim3(1024), dim3(256), 0, stream>>>(Qb, Kb, Vb, AObf);
  proj_kernel<<<dim3(128, 2), dim3(256), 0, stream>>>(AObf, Wproj, projb, x, X1);
  ln_kernel<<<dim3(256), dim3(256), 0, stream>>>(X1, ln2w, ln2b, XLN2);
  fc1_kernel<<<dim3(128, 4), dim3(256), 0, stream>>>(XLN2, Wfc1, fc1b, HB);
  fc2_kernel<<<dim3(128, 2), dim3(256), 0, stream>>>(HB, Wfc2, fc2b, X1, out);
}

// Round 9
// 236.384 us; speedup vs baseline: 1.7052x; 1.0452x over previous
//
#include <hip/hip_runtime.h>
#include <hip/hip_bf16.h>

// ---------------------------------------------------------------------------
// MHSA + MLP block, B=4 C=128 H=W=64 (N=4096), HEADS=4 HD=32, HIDDEN=256.
// All GEMMs bf16 MFMA (16x16x32), activations bf16, residual spine fp32.
// Attn: swapped-operand flash, C-operand max-fold, defer-max (THR=8),
//       MFMA-ones l-sum, lane-local softmax, P in-register.
// ws layout (bytes): WB bf16 weights [0,1M), XLN/AO bf16 [1M,5M),
//   Qb/XLN2 [5M,9M), Kb [9M,13M), Vb [13M,17M), H bf16 [9M,17M) after attn,
//   X1 f32 [17M,25M).  Total 25 MB.
// ---------------------------------------------------------------------------

typedef __attribute__((ext_vector_type(4))) float f32x4;
typedef __attribute__((ext_vector_type(8))) short bf16x8;       // MFMA A/B frag
typedef __attribute__((ext_vector_type(8))) unsigned short ushort8;
typedef __attribute__((ext_vector_type(4))) unsigned short ushort4v;

#define C_ 128
#define N_ 4096
#define SL2E 0.25504712280087033f   // (1/sqrt(32)) * log2(e)

__device__ inline unsigned short f2bf(float f) {   // fp32 -> bf16 RNE
  unsigned int x = __float_as_uint(f);
  x += 0x7fffu + ((x >> 16) & 1u);
  return (unsigned short)(x >> 16);
}

__device__ inline unsigned int pk2(float a, float b) {  // pack 2xbf16 word
  __hip_bfloat162 h2 = __float22bfloat162_rn(make_float2(a, b));
  return *(unsigned int*)&h2;
}

// Weight conversion: qkv_w(49152) | proj_w(16384) | fc1_w(32768) | fc2_w(32768)
__global__ __launch_bounds__(256) void wconv_kernel(const float* __restrict__ qkvw,
                                                    const float* __restrict__ projw,
                                                    const float* __restrict__ fc1w,
                                                    const float* __restrict__ fc2w,
                                                    unsigned short* __restrict__ WB) {
  int i = blockIdx.x * 256 + threadIdx.x;       // grid 512 -> 131072
  float v;
  if (i < 49152) v = qkvw[i];
  else if (i < 65536) v = projw[i - 49152];
  else if (i < 98304) v = fc1w[i - 65536];
  else v = fc2w[i - 98304];
  WB[i] = f2bf(v);
}

// ---------------------------------------------------------------------------
// LayerNorm over channels. Input [B,C,N] (NCHW) f32, output rows [B*N, C] bf16.
// ---------------------------------------------------------------------------
__global__ __launch_bounds__(256) void ln_kernel(const float* __restrict__ xin,
                                                 const float* __restrict__ gamma,
                                                 const float* __restrict__ beta,
                                                 unsigned short* __restrict__ outp) {
  __shared__ float tile[128][65];
  __shared__ float ps[4][64];
  __shared__ float pss[4][64];
  __shared__ float mu_s[64];
  __shared__ float rs_s[64];
  const int t = threadIdx.x;
  const int b = blockIdx.x >> 6;
  const int n0 = (blockIdx.x & 63) << 6;
  const float* xb = xin + (size_t)b * C_ * N_ + n0;
#pragma unroll
  for (int i = 0; i < 32; ++i) {
    int lin = i * 256 + t;
    int c = lin >> 6, p = lin & 63;
    tile[c][p] = xb[(size_t)c * N_ + p];
  }
  __syncthreads();
  {
    int p = t & 63, part = t >> 6;
    float s = 0.f, ss = 0.f;
#pragma unroll
    for (int j = 0; j < 32; ++j) {
      float v = tile[part * 32 + j][p];
      s += v; ss += v * v;
    }
    ps[part][p] = s; pss[part][p] = ss;
  }
  __syncthreads();
  if (t < 64) {
    int p = t;
    float su = ps[0][p] + ps[1][p] + ps[2][p] + ps[3][p];
    float sq = pss[0][p] + pss[1][p] + pss[2][p] + pss[3][p];
    float mu = su * (1.f / 128.f);
    float var = sq * (1.f / 128.f) - mu * mu;
    mu_s[p] = mu;
    rs_s[p] = rsqrtf(var + 1e-5f);
  }
  __syncthreads();
  unsigned short* ob = outp + (size_t)(b * N_ + n0) * C_;
#pragma unroll
  for (int i = 0; i < 16; ++i) {            // 64 pos x 128 ch, 2 ch per thread
    int lin = i * 256 + t;
    int p = lin >> 6, c2 = (lin & 63) << 1;
    float mu = mu_s[p], rs = rs_s[p];
    float a = (tile[c2][p] - mu) * rs * gamma[c2] + beta[c2];
    float d = (tile[c2 + 1][p] - mu) * rs * gamma[c2 + 1] + beta[c2 + 1];
    *(unsigned int*)&ob[(size_t)p * C_ + c2] = pk2(a, d);
  }
}

// ---------------------------------------------------------------------------
// bf16 MFMA GEMM core (128x64 tile, XOR-swizzled LDS, 4 waves).
// ---------------------------------------------------------------------------
template <int KD>
__device__ inline void mfma_core(const unsigned short* __restrict__ A,
                                 const unsigned short* __restrict__ W,
                                 int row0, int col0, f32x4 acc[2][4]) {
  __shared__ __align__(16) unsigned short As[128][128];
  __shared__ __align__(16) unsigned short Ws[64][128];
  const int t = threadIdx.x;
  const int w = t >> 6, lane = t & 63;
  const int l15 = lane & 15, g = lane >> 4;
  const int srow = t >> 4, schunk = t & 15;    // staging: 16 thr cover one row
#pragma unroll
  for (int kt = 0; kt < KD / 128; ++kt) {
    __syncthreads();
#pragma unroll
    for (int i = 0; i < 8; ++i) {              // A tile 128x128
      int row = i * 16 + srow;
      int c = schunk ^ (row & 7);
      *(ushort8*)&As[row][c * 8] =
          *(const ushort8*)&A[(size_t)(row0 + row) * KD + kt * 128 + schunk * 8];
    }
#pragma unroll
    for (int i = 0; i < 4; ++i) {              // W tile 64x128
      int row = i * 16 + srow;
      int c = schunk ^ (row & 7);
      *(ushort8*)&Ws[row][c * 8] =
          *(const ushort8*)&W[(size_t)(col0 + row) * KD + kt * 128 + schunk * 8];
    }
    __syncthreads();
#pragma unroll
    for (int kk = 0; kk < 4; ++kk) {
      bf16x8 aA[2], bW[4];
#pragma unroll
      for (int mi = 0; mi < 2; ++mi) {
        int mrow = (w << 5) + (mi << 4) + l15;
        int c = (kk * 4 + g) ^ (mrow & 7);
        aA[mi] = *(const bf16x8*)&As[mrow][c * 8];
      }
#pragma unroll
      for (int nj = 0; nj < 4; ++nj) {
        int wrow = (nj << 4) + l15;
        int c = (kk * 4 + g) ^ (wrow & 7);
        bW[nj] = *(const bf16x8*)&Ws[wrow][c * 8];
      }
#pragma unroll
      for (int mi = 0; mi < 2; ++mi)
#pragma unroll
        for (int nj = 0; nj < 4; ++nj)
          acc[mi][nj] = __builtin_amdgcn_mfma_f32_16x16x32_bf16(aA[mi], bW[nj],
                                                                acc[mi][nj], 0, 0, 0);
    }
  }
}

// QKV: XLN [16384,128] x WB[384,128] -> bf16 Q,K [bh][n][32], V [bh][32][n].
__global__ __launch_bounds__(256) void qkv_kernel(const unsigned short* __restrict__ XLN,
                                                  const unsigned short* __restrict__ Wq,
                                                  unsigned short* __restrict__ Qb,
                                                  unsigned short* __restrict__ Kb,
                                                  unsigned short* __restrict__ Vb) {
  const int row0 = blockIdx.x << 7, col0 = blockIdx.y << 6;
  f32x4 acc[2][4] = {};
  mfma_core<128>(XLN, Wq, row0, col0, acc);
  const int t = threadIdx.x, w = t >> 6, lane = t & 63;
  const int l15 = lane & 15, g = lane >> 4;
#pragma unroll
  for (int mi = 0; mi < 2; ++mi) {
    int grow = row0 + (w << 5) + (mi << 4) + (g << 2);
    int b = grow >> 12, n0 = grow & 4095;
#pragma unroll
    for (int nj = 0; nj < 4; ++nj) {
      int o = col0 + (nj << 4) + l15;
      int ch = o & 127, hh = ch >> 5, d = ch & 31;
      f32x4 a = acc[mi][nj];
      if (o < 128) {
        size_t base = ((size_t)(b * 4 + hh) * 4096 + n0) * 32 + d;
#pragma unroll
        for (int r = 0; r < 4; ++r) Qb[base + (size_t)r * 32] = f2bf(a[r] * SL2E);
      } else if (o < 256) {
        size_t base = ((size_t)(b * 4 + hh) * 4096 + n0) * 32 + d;
#pragma unroll
        for (int r = 0; r < 4; ++r) Kb[base + (size_t)r * 32] = f2bf(a[r]);
      } else {
        ushort4v u = {f2bf(a[0]), f2bf(a[1]), f2bf(a[2]), f2bf(a[3])};
        *(ushort4v*)&Vb[((size_t)(b * 4 + hh) * 32 + d) * 4096 + n0] = u;
      }
    }
  }
}

// ---------------------------------------------------------------------------
// Flash attention, swapped-operand bf16 MFMA, slim softmax:
//  - s' = mfma(K, Q^T, -m_r) : running max folded into MFMA C-operand
//  - defer-max THR=8 (base-2): common path has NO rescale, NO cross-lane ops
//  - l-sum via mfma(ones, P) on the idle matrix pipe (kills VALU adds +
//    epilogue reduce)
// ---------------------------------------------------------------------------
__global__ __launch_bounds__(256) void attn_kernel(const unsigned short* __restrict__ Qg,
                                                   const unsigned short* __restrict__ Kg,
                                                   const unsigned short* __restrict__ Vg,
                                                   unsigned short* __restrict__ AO) {
  __shared__ __align__(16) unsigned short Qa[64][40];
  __shared__ __align__(16) unsigned short Ks[2][64][40];
  __shared__ __align__(16) unsigned short Vt[2][32][72];
  const int id = blockIdx.x;                     // grid 1024
  const int bh = (id & 7) | ((id >> 9) << 3);    // xcd = bh % 8 (K/V L2-resident)
  const int qt = (id >> 3) & 63;
  const int b = bh >> 2, h = bh & 3;
  const unsigned short* Qp = Qg + ((size_t)bh * 4096 + qt * 64) * 32;
  const unsigned short* Kp = Kg + (size_t)bh * 4096 * 32;
  const unsigned short* Vp = Vg + (size_t)bh * 32 * 4096;
  const int t = threadIdx.x;
  const int lane = t & 63, w = t >> 6;
  const int l15 = lane & 15, g = lane >> 4;
  const int krow = t >> 2, kd0 = (t & 3) << 3;   // K/Q staging coords
  const int vd = t >> 3, vc = t & 7;             // V staging: row, key-octet
  const int vpos = ((vc >> 2) << 5) + ((vc & 1) << 4) + (((vc & 3) >> 1) << 2);

  *(ushort8*)&Qa[krow][kd0] = *(const ushort8*)(Qp + krow * 32 + kd0);
  ushort8 kreg = *(const ushort8*)(Kp + (size_t)krow * 32 + kd0);
  ushort8 vreg = *(const ushort8*)(Vp + (size_t)vd * 4096 + (vc << 3));
  *(ushort8*)&Ks[0][krow][kd0] = kreg;
  {
    ushort4v lo = {vreg[0], vreg[1], vreg[2], vreg[3]};
    ushort4v hi = {vreg[4], vreg[5], vreg[6], vreg[7]};
    *(ushort4v*)&Vt[0][vd][vpos] = lo;
    *(ushort4v*)&Vt[0][vd][vpos + 8] = hi;
  }
  __syncthreads();
  const bf16x8 aQ = *(const bf16x8*)&Qa[(w << 4) + l15][g << 3];
  const short oneb = (short)0x3F80;              // bf16 1.0
  const bf16x8 ones = {oneb, oneb, oneb, oneb, oneb, oneb, oneb, oneb};

  const f32x4 zero = {0.f, 0.f, 0.f, 0.f};
  f32x4 opv[2]; opv[0] = zero; opv[1] = zero;
  f32x4 lsum = zero;
  f32x4 cneg = zero;                             // splat(-m_r)
  float m_r = 0.f;

  for (int kt = 0; kt < 64; ++kt) {
    const int cur = kt & 1;
    if (kt < 63) {
      kreg = *(const ushort8*)(Kp + (size_t)((kt + 1) * 64 + krow) * 32 + kd0);
      vreg = *(const ushort8*)(Vp + (size_t)vd * 4096 + (kt + 1) * 64 + (vc << 3));
    }

    f32x4 s[4];
#pragma unroll
    for (int ks = 0; ks < 4; ++ks) {   // s' = S^T - m_r  (C-operand fold)
      bf16x8 bK = *(const bf16x8*)&Ks[cur][(ks << 4) + l15][g << 3];
      s[ks] = __builtin_amdgcn_mfma_f32_16x16x32_bf16(bK, aQ, cneg, 0, 0, 0);
    }

    // lane-local max of 16 rel-logits (max3-fused triples)
    float a0 = fmaxf(fmaxf(s[0][0], s[0][1]), s[0][2]);
    float a1 = fmaxf(fmaxf(s[0][3], s[1][0]), s[1][1]);
    float a2 = fmaxf(fmaxf(s[1][2], s[1][3]), s[2][0]);
    float a3 = fmaxf(fmaxf(s[2][1], s[2][2]), s[2][3]);
    float a4 = fmaxf(fmaxf(s[3][0], s[3][1]), s[3][2]);
    float m0 = fmaxf(fmaxf(fmaxf(a0, a1), fmaxf(a2, a3)), fmaxf(a4, s[3][3]));

    float p[4][4];
    if (__builtin_expect(!__all(m0 <= 8.f), 0)) {
      // rare rescale path: cross-g true max, shift running max
      m0 = fmaxf(m0, __shfl_xor(m0, 16));
      m0 = fmaxf(m0, __shfl_xor(m0, 32));
      float d = fmaxf(m0, 0.f);
      float al = exp2f(-d);
      m_r += d;
      cneg = zero - m_r;                        // rebuild splat(-m_r)
      opv[0] *= al;
      opv[1] *= al;
      lsum *= al;
#pragma unroll
      for (int ks = 0; ks < 4; ++ks)
#pragma unroll
        for (int r = 0; r < 4; ++r) p[ks][r] = exp2f(s[ks][r] - d);
    } else {
#pragma unroll
      for (int ks = 0; ks < 4; ++ks)
#pragma unroll
        for (int r = 0; r < 4; ++r) p[ks][r] = exp2f(s[ks][r]);
    }

#pragma unroll
    for (int pi = 0; pi < 2; ++pi) {
      union { unsigned int u[4]; bf16x8 v; } bP;
      bP.u[0] = pk2(p[2 * pi][0], p[2 * pi][1]);
      bP.u[1] = pk2(p[2 * pi][2], p[2 * pi][3]);
      bP.u[2] = pk2(p[2 * pi + 1][0], p[2 * pi + 1][1]);
      bP.u[3] = pk2(p[2 * pi + 1][2], p[2 * pi + 1][3]);
      lsum = __builtin_amdgcn_mfma_f32_16x16x32_bf16(ones, bP.v, lsum, 0, 0, 0);
#pragma unroll
      for (int dt = 0; dt < 2; ++dt) {
        bf16x8 aV = *(const bf16x8*)&Vt[cur][(dt << 4) + l15][(pi << 5) + (g << 3)];
        opv[dt] = __builtin_amdgcn_mfma_f32_16x16x32_bf16(aV, bP.v, opv[dt], 0, 0, 0);
      }
    }

    if (kt < 63) {
      *(ushort8*)&Ks[cur ^ 1][krow][kd0] = kreg;
      ushort4v lo = {vreg[0], vreg[1], vreg[2], vreg[3]};
      ushort4v hi = {vreg[4], vreg[5], vreg[6], vreg[7]};
      *(ushort4v*)&Vt[cur ^ 1][vd][vpos] = lo;
      *(ushort4v*)&Vt[cur ^ 1][vd][vpos + 8] = hi;
    }
    __syncthreads();
  }

  // lsum rows are identical (ones matrix) -> per-lane l with no reduce
  float inv = 1.f / lsum[0];
  const int n = qt * 64 + (w << 4) + l15;
  unsigned short* aob = AO + (size_t)(b * 4096 + n) * 128 + (h << 5);
#pragma unroll
  for (int dt = 0; dt < 2; ++dt) {
    f32x4 o = opv[dt] * inv;
    ushort4v u = {f2bf(o[0]), f2bf(o[1]), f2bf(o[2]), f2bf(o[3])};
    *(ushort4v*)&aob[(dt << 4) + (g << 2)] = u;
  }
}

// proj + residual: X1[b,c,n] (f32) = x + AO.proj_w + proj_b
__global__ __launch_bounds__(256) void proj_kernel(const unsigned short* __restrict__ AO,
                                                   const unsigned short* __restrict__ Wp,
                                                   const float* __restrict__ bp,
                                                   const float* __restrict__ x,
                                                   float* __restrict__ X1) {
  const int row0 = blockIdx.x << 7, col0 = blockIdx.y << 6;
  f32x4 acc[2][4] = {};
  mfma_core<128>(AO, Wp, row0, col0, acc);
  const int t = threadIdx.x, w = t >> 6, lane = t & 63;
  const int l15 = lane & 15, g = lane >> 4;
#pragma unroll
  for (int mi = 0; mi < 2; ++mi) {
    int grow = row0 + (w << 5) + (mi << 4) + (g << 2);
    int b = grow >> 12, n0 = grow & 4095;
#pragma unroll
    for (int nj = 0; nj < 4; ++nj) {
      int c = col0 + (nj << 4) + l15;
      size_t idx = ((size_t)(b * C_ + c) << 12) + n0;
      f32x4 xv = *(const f32x4*)&x[idx];
      f32x4 r = xv + acc[mi][nj] + bp[c];
      *(f32x4*)&X1[idx] = r;
    }
  }
}

// fc1 + exact GELU -> H bf16 [16384, 256]
__global__ __launch_bounds__(256) void fc1_kernel(const unsigned short* __restrict__ XLN2,
                                                  const unsigned short* __restrict__ W1,
                                                  const float* __restrict__ b1,
                                                  unsigned short* __restrict__ Hb) {
  const int row0 = blockIdx.x << 7, col0 = blockIdx.y << 6;
  f32x4 acc[2][4] = {};
  mfma_core<128>(XLN2, W1, row0, col0, acc);
  const int t = threadIdx.x, w = t >> 6, lane = t & 63;
  const int l15 = lane & 15, g = lane >> 4;
#pragma unroll
  for (int mi = 0; mi < 2; ++mi) {
    int grow = row0 + (w << 5) + (mi << 4) + (g << 2);
#pragma unroll
    for (int nj = 0; nj < 4; ++nj) {
      int o = col0 + (nj << 4) + l15;
      float bb = b1[o];
#pragma unroll
      for (int r = 0; r < 4; ++r) {
        float v = acc[mi][nj][r] + bb;
        v = 0.5f * v * (1.f + erff(v * 0.70710678118654752f));
        Hb[(size_t)(grow + r) * 256 + o] = f2bf(v);
      }
    }
  }
}

// fc2 + residual -> out f32 NCHW
__global__ __launch_bounds__(256) void fc2_kernel(const unsigned short* __restrict__ Hb,
                                                  const unsigned short* __restrict__ W2,
                                                  const float* __restrict__ b2,
                                                  const float* __restrict__ X1,
                                                  float* __restrict__ outp) {
  const int row0 = blockIdx.x << 7, col0 = blockIdx.y << 6;
  f32x4 acc[2][4] = {};
  mfma_core<256>(Hb, W2, row0, col0, acc);
  const int t = threadIdx.x, w = t >> 6, lane = t & 63;
  const int l15 = lane & 15, g = lane >> 4;
#pragma unroll
  for (int mi = 0; mi < 2; ++mi) {
    int grow = row0 + (w << 5) + (mi << 4) + (g << 2);
    int b = grow >> 12, n0 = grow & 4095;
#pragma unroll
    for (int nj = 0; nj < 4; ++nj) {
      int c = col0 + (nj << 4) + l15;
      size_t idx = ((size_t)(b * C_ + c) << 12) + n0;
      f32x4 xv = *(const f32x4*)&X1[idx];
      f32x4 r = xv + acc[mi][nj] + b2[c];
      *(f32x4*)&outp[idx] = r;
    }
  }
}

extern "C" void kernel_launch(void* const* d_in, const int* in_sizes, int n_in,
                              void* d_out, int out_size, void* d_ws, size_t ws_size,
                              hipStream_t stream) {
  (void)in_sizes; (void)n_in; (void)out_size; (void)ws_size;
  const float* x     = (const float*)d_in[0];
  const float* ln1w  = (const float*)d_in[1];
  const float* ln1b  = (const float*)d_in[2];
  const float* qkvw  = (const float*)d_in[3];
  const float* projw = (const float*)d_in[4];
  const float* projb = (const float*)d_in[5];
  const float* ln2w  = (const float*)d_in[6];
  const float* ln2b  = (const float*)d_in[7];
  const float* fc1w  = (const float*)d_in[8];
  const float* fc1b  = (const float*)d_in[9];
  const float* fc2w  = (const float*)d_in[10];
  const float* fc2b  = (const float*)d_in[11];
  float* out = (float*)d_out;
  char* ws8 = (char*)d_ws;

  const size_t MB = 1u << 20;
  unsigned short* WB   = (unsigned short*)(ws8);            // 256 KB used
  unsigned short* XLN  = (unsigned short*)(ws8 + 1 * MB);   // 4 MB, reused as AO
  unsigned short* Qb   = (unsigned short*)(ws8 + 5 * MB);   // 4 MB, reused as XLN2
  unsigned short* Kb   = (unsigned short*)(ws8 + 9 * MB);   // 4 MB
  unsigned short* Vb   = (unsigned short*)(ws8 + 13 * MB);  // 4 MB
  unsigned short* AObf = XLN;                               // after qkv
  unsigned short* XLN2 = Qb;                                // after attn
  unsigned short* HB   = Kb;                                // 8 MB (K+V), after attn
  float*          X1   = (float*)(ws8 + 17 * MB);           // 8 MB
  const unsigned short* Wqkv = WB;
  const unsigned short* Wproj = WB + 49152;
  const unsigned short* Wfc1 = WB + 65536;
  const unsigned short* Wfc2 = WB + 98304;

  wconv_kernel<<<dim3(512), dim3(256), 0, stream>>>(qkvw, projw, fc1w, fc2w, WB);
  ln_kernel<<<dim3(256), dim3(256), 0, stream>>>(x, ln1w, ln1b, XLN);
  qkv_kernel<<<dim3(128, 6), dim3(256), 0, stream>>>(XLN, Wqkv, Qb, Kb, Vb);
  attn_kernel<<<dim3(1024), dim3(256), 0, stream>>>(Qb, Kb, Vb, AObf);
  proj_kernel<<<dim3(128, 2), dim3(256), 0, stream>>>(AObf, Wproj, projb, x, X1);
  ln_kernel<<<dim3(256), dim3(256), 0, stream>>>(X1, ln2w, ln2b, XLN2);
  fc1_kernel<<<dim3(128, 4), dim3(256), 0, stream>>>(XLN2, Wfc1, fc1b, HB);
  fc2_kernel<<<dim3(128, 2), dim3(256), 0, stream>>>(HB, Wfc2, fc2b, X1, out);
}

// Round 10
// 205.598 us; speedup vs baseline: 1.9605x; 1.1497x over previous
//
#include <hip/hip_runtime.h>
#include <hip/hip_bf16.h>

// ---------------------------------------------------------------------------
// MHSA + MLP block, B=4 C=128 H=W=64 (N=4096), HEADS=4 HD=32, HIDDEN=256.
// All GEMMs bf16 MFMA (16x16x32), activations bf16, residual spine fp32.
// Attn: swapped-operand flash, C-operand max-fold, defer-max (THR=8),
//       MFMA-ones l-sum, raw v_exp_f32, pointer-increment staging.
// ws layout (bytes): WB bf16 weights [0,1M), XLN/AO bf16 [1M,5M),
//   Qb/XLN2 [5M,9M), Kb [9M,13M), Vb [13M,17M), H bf16 [9M,17M) after attn,
//   X1 f32 [17M,25M).  Total 25 MB.
// ---------------------------------------------------------------------------

typedef __attribute__((ext_vector_type(4))) float f32x4;
typedef __attribute__((ext_vector_type(8))) short bf16x8;       // MFMA A/B frag
typedef __attribute__((ext_vector_type(8))) unsigned short ushort8;
typedef __attribute__((ext_vector_type(4))) unsigned short ushort4v;

#define C_ 128
#define N_ 4096
#define SL2E 0.25504712280087033f   // (1/sqrt(32)) * log2(e)
#define EXP2R(x) __builtin_amdgcn_exp2f(x)   // bare v_exp_f32, no OCML guard

__device__ inline unsigned short f2bf(float f) {   // fp32 -> bf16 RNE
  unsigned int x = __float_as_uint(f);
  x += 0x7fffu + ((x >> 16) & 1u);
  return (unsigned short)(x >> 16);
}

__device__ inline unsigned int pk2(float a, float b) {  // pack 2xbf16 word
  __hip_bfloat162 h2 = __float22bfloat162_rn(make_float2(a, b));
  return *(unsigned int*)&h2;
}

// Weight conversion: qkv_w(49152) | proj_w(16384) | fc1_w(32768) | fc2_w(32768)
__global__ __launch_bounds__(256) void wconv_kernel(const float* __restrict__ qkvw,
                                                    const float* __restrict__ projw,
                                                    const float* __restrict__ fc1w,
                                                    const float* __restrict__ fc2w,
                                                    unsigned short* __restrict__ WB) {
  int i = blockIdx.x * 256 + threadIdx.x;       // grid 512 -> 131072
  float v;
  if (i < 49152) v = qkvw[i];
  else if (i < 65536) v = projw[i - 49152];
  else if (i < 98304) v = fc1w[i - 65536];
  else v = fc2w[i - 98304];
  WB[i] = f2bf(v);
}

// ---------------------------------------------------------------------------
// LayerNorm over channels. Input [B,C,N] (NCHW) f32, output rows [B*N, C] bf16.
// ---------------------------------------------------------------------------
__global__ __launch_bounds__(256) void ln_kernel(const float* __restrict__ xin,
                                                 const float* __restrict__ gamma,
                                                 const float* __restrict__ beta,
                                                 unsigned short* __restrict__ outp) {
  __shared__ float tile[128][65];
  __shared__ float ps[4][64];
  __shared__ float pss[4][64];
  __shared__ float mu_s[64];
  __shared__ float rs_s[64];
  const int t = threadIdx.x;
  const int b = blockIdx.x >> 6;
  const int n0 = (blockIdx.x & 63) << 6;
  const float* xb = xin + (size_t)b * C_ * N_ + n0;
#pragma unroll
  for (int i = 0; i < 32; ++i) {
    int lin = i * 256 + t;
    int c = lin >> 6, p = lin & 63;
    tile[c][p] = xb[(size_t)c * N_ + p];
  }
  __syncthreads();
  {
    int p = t & 63, part = t >> 6;
    float s = 0.f, ss = 0.f;
#pragma unroll
    for (int j = 0; j < 32; ++j) {
      float v = tile[part * 32 + j][p];
      s += v; ss += v * v;
    }
    ps[part][p] = s; pss[part][p] = ss;
  }
  __syncthreads();
  if (t < 64) {
    int p = t;
    float su = ps[0][p] + ps[1][p] + ps[2][p] + ps[3][p];
    float sq = pss[0][p] + pss[1][p] + pss[2][p] + pss[3][p];
    float mu = su * (1.f / 128.f);
    float var = sq * (1.f / 128.f) - mu * mu;
    mu_s[p] = mu;
    rs_s[p] = rsqrtf(var + 1e-5f);
  }
  __syncthreads();
  unsigned short* ob = outp + (size_t)(b * N_ + n0) * C_;
#pragma unroll
  for (int i = 0; i < 16; ++i) {            // 64 pos x 128 ch, 2 ch per thread
    int lin = i * 256 + t;
    int p = lin >> 6, c2 = (lin & 63) << 1;
    float mu = mu_s[p], rs = rs_s[p];
    float a = (tile[c2][p] - mu) * rs * gamma[c2] + beta[c2];
    float d = (tile[c2 + 1][p] - mu) * rs * gamma[c2 + 1] + beta[c2 + 1];
    *(unsigned int*)&ob[(size_t)p * C_ + c2] = pk2(a, d);
  }
}

// ---------------------------------------------------------------------------
// bf16 MFMA GEMM core (128x64 tile, XOR-swizzled LDS, 4 waves).
// ---------------------------------------------------------------------------
template <int KD>
__device__ inline void mfma_core(const unsigned short* __restrict__ A,
                                 const unsigned short* __restrict__ W,
                                 int row0, int col0, f32x4 acc[2][4]) {
  __shared__ __align__(16) unsigned short As[128][128];
  __shared__ __align__(16) unsigned short Ws[64][128];
  const int t = threadIdx.x;
  const int w = t >> 6, lane = t & 63;
  const int l15 = lane & 15, g = lane >> 4;
  const int srow = t >> 4, schunk = t & 15;    // staging: 16 thr cover one row
#pragma unroll
  for (int kt = 0; kt < KD / 128; ++kt) {
    __syncthreads();
#pragma unroll
    for (int i = 0; i < 8; ++i) {              // A tile 128x128
      int row = i * 16 + srow;
      int c = schunk ^ (row & 7);
      *(ushort8*)&As[row][c * 8] =
          *(const ushort8*)&A[(size_t)(row0 + row) * KD + kt * 128 + schunk * 8];
    }
#pragma unroll
    for (int i = 0; i < 4; ++i) {              // W tile 64x128
      int row = i * 16 + srow;
      int c = schunk ^ (row & 7);
      *(ushort8*)&Ws[row][c * 8] =
          *(const ushort8*)&W[(size_t)(col0 + row) * KD + kt * 128 + schunk * 8];
    }
    __syncthreads();
#pragma unroll
    for (int kk = 0; kk < 4; ++kk) {
      bf16x8 aA[2], bW[4];
#pragma unroll
      for (int mi = 0; mi < 2; ++mi) {
        int mrow = (w << 5) + (mi << 4) + l15;
        int c = (kk * 4 + g) ^ (mrow & 7);
        aA[mi] = *(const bf16x8*)&As[mrow][c * 8];
      }
#pragma unroll
      for (int nj = 0; nj < 4; ++nj) {
        int wrow = (nj << 4) + l15;
        int c = (kk * 4 + g) ^ (wrow & 7);
        bW[nj] = *(const bf16x8*)&Ws[wrow][c * 8];
      }
#pragma unroll
      for (int mi = 0; mi < 2; ++mi)
#pragma unroll
        for (int nj = 0; nj < 4; ++nj)
          acc[mi][nj] = __builtin_amdgcn_mfma_f32_16x16x32_bf16(aA[mi], bW[nj],
                                                                acc[mi][nj], 0, 0, 0);
    }
  }
}

// QKV: XLN [16384,128] x WB[384,128] -> bf16 Q,K [bh][n][32], V [bh][32][n].
__global__ __launch_bounds__(256) void qkv_kernel(const unsigned short* __restrict__ XLN,
                                                  const unsigned short* __restrict__ Wq,
                                                  unsigned short* __restrict__ Qb,
                                                  unsigned short* __restrict__ Kb,
                                                  unsigned short* __restrict__ Vb) {
  const int row0 = blockIdx.x << 7, col0 = blockIdx.y << 6;
  f32x4 acc[2][4] = {};
  mfma_core<128>(XLN, Wq, row0, col0, acc);
  const int t = threadIdx.x, w = t >> 6, lane = t & 63;
  const int l15 = lane & 15, g = lane >> 4;
#pragma unroll
  for (int mi = 0; mi < 2; ++mi) {
    int grow = row0 + (w << 5) + (mi << 4) + (g << 2);
    int b = grow >> 12, n0 = grow & 4095;
#pragma unroll
    for (int nj = 0; nj < 4; ++nj) {
      int o = col0 + (nj << 4) + l15;
      int ch = o & 127, hh = ch >> 5, d = ch & 31;
      f32x4 a = acc[mi][nj];
      if (o < 128) {
        size_t base = ((size_t)(b * 4 + hh) * 4096 + n0) * 32 + d;
#pragma unroll
        for (int r = 0; r < 4; ++r) Qb[base + (size_t)r * 32] = f2bf(a[r] * SL2E);
      } else if (o < 256) {
        size_t base = ((size_t)(b * 4 + hh) * 4096 + n0) * 32 + d;
#pragma unroll
        for (int r = 0; r < 4; ++r) Kb[base + (size_t)r * 32] = f2bf(a[r]);
      } else {
        ushort4v u = {f2bf(a[0]), f2bf(a[1]), f2bf(a[2]), f2bf(a[3])};
        *(ushort4v*)&Vb[((size_t)(b * 4 + hh) * 32 + d) * 4096 + n0] = u;
      }
    }
  }
}

// ---------------------------------------------------------------------------
// Flash attention, swapped-operand bf16 MFMA, slim softmax:
//  - s' = mfma(K, Q^T, -m_r) : running max folded into MFMA C-operand
//  - defer-max THR=8 (base-2): common path has NO rescale, NO cross-lane ops
//  - l-sum via mfma(ones, P) on the idle matrix pipe
//  - EXP2R = raw v_exp_f32 (no OCML denormal guard)
//  - K/V prefetch via incrementing pointers (no per-chunk 64-bit mul chains)
// ---------------------------------------------------------------------------
__global__ __launch_bounds__(256) void attn_kernel(const unsigned short* __restrict__ Qg,
                                                   const unsigned short* __restrict__ Kg,
                                                   const unsigned short* __restrict__ Vg,
                                                   unsigned short* __restrict__ AO) {
  __shared__ __align__(16) unsigned short Qa[64][40];
  __shared__ __align__(16) unsigned short Ks[2][64][40];
  __shared__ __align__(16) unsigned short Vt[2][32][72];
  const int id = blockIdx.x;                     // grid 1024
  const int bh = (id & 7) | ((id >> 9) << 3);    // xcd = bh % 8 (K/V L2-resident)
  const int qt = (id >> 3) & 63;
  const int b = bh >> 2, h = bh & 3;
  const unsigned short* Qp = Qg + ((size_t)bh * 4096 + qt * 64) * 32;
  const unsigned short* Kp = Kg + (size_t)bh * 4096 * 32;
  const unsigned short* Vp = Vg + (size_t)bh * 32 * 4096;
  const int t = threadIdx.x;
  const int lane = t & 63, w = t >> 6;
  const int l15 = lane & 15, g = lane >> 4;
  const int krow = t >> 2, kd0 = (t & 3) << 3;   // K/Q staging coords
  const int vd = t >> 3, vc = t & 7;             // V staging: row, key-octet
  const int vpos = ((vc >> 2) << 5) + ((vc & 1) << 4) + (((vc & 3) >> 1) << 2);

  *(ushort8*)&Qa[krow][kd0] = *(const ushort8*)(Qp + krow * 32 + kd0);
  ushort8 kreg = *(const ushort8*)(Kp + (size_t)krow * 32 + kd0);
  ushort8 vreg = *(const ushort8*)(Vp + (size_t)vd * 4096 + (vc << 3));
  // incrementing prefetch pointers (chunk kt+1)
  const unsigned short* kp_n = Kp + 64 * 32 + (size_t)krow * 32 + kd0;
  const unsigned short* vp_n = Vp + (size_t)vd * 4096 + 64 + (vc << 3);
  *(ushort8*)&Ks[0][krow][kd0] = kreg;
  {
    ushort4v lo = {vreg[0], vreg[1], vreg[2], vreg[3]};
    ushort4v hi = {vreg[4], vreg[5], vreg[6], vreg[7]};
    *(ushort4v*)&Vt[0][vd][vpos] = lo;
    *(ushort4v*)&Vt[0][vd][vpos + 8] = hi;
  }
  __syncthreads();
  const bf16x8 aQ = *(const bf16x8*)&Qa[(w << 4) + l15][g << 3];
  const short oneb = (short)0x3F80;              // bf16 1.0
  const bf16x8 ones = {oneb, oneb, oneb, oneb, oneb, oneb, oneb, oneb};

  const f32x4 zero = {0.f, 0.f, 0.f, 0.f};
  f32x4 opv[2]; opv[0] = zero; opv[1] = zero;
  f32x4 lsum = zero;
  f32x4 cneg = zero;                             // splat(-m_r)
  float m_r = 0.f;

  for (int kt = 0; kt < 64; ++kt) {
    const int cur = kt & 1;
    if (kt < 63) {
      kreg = *(const ushort8*)kp_n;  kp_n += 64 * 32;
      vreg = *(const ushort8*)vp_n;  vp_n += 64;
    }

    f32x4 s[4];
#pragma unroll
    for (int ks = 0; ks < 4; ++ks) {   // s' = S^T - m_r  (C-operand fold)
      bf16x8 bK = *(const bf16x8*)&Ks[cur][(ks << 4) + l15][g << 3];
      s[ks] = __builtin_amdgcn_mfma_f32_16x16x32_bf16(bK, aQ, cneg, 0, 0, 0);
    }

    // lane-local max of 16 rel-logits (max3-fused triples)
    float a0 = fmaxf(fmaxf(s[0][0], s[0][1]), s[0][2]);
    float a1 = fmaxf(fmaxf(s[0][3], s[1][0]), s[1][1]);
    float a2 = fmaxf(fmaxf(s[1][2], s[1][3]), s[2][0]);
    float a3 = fmaxf(fmaxf(s[2][1], s[2][2]), s[2][3]);
    float a4 = fmaxf(fmaxf(s[3][0], s[3][1]), s[3][2]);
    float m0 = fmaxf(fmaxf(fmaxf(a0, a1), fmaxf(a2, a3)), fmaxf(a4, s[3][3]));

    float p[4][4];
    if (__builtin_expect(!__all(m0 <= 8.f), 0)) {
      // rare rescale path: cross-g true max, shift running max
      m0 = fmaxf(m0, __shfl_xor(m0, 16));
      m0 = fmaxf(m0, __shfl_xor(m0, 32));
      float d = fmaxf(m0, 0.f);
      float al = EXP2R(-d);
      m_r += d;
      cneg = zero - m_r;                        // rebuild splat(-m_r)
      opv[0] *= al;
      opv[1] *= al;
      lsum *= al;
#pragma unroll
      for (int ks = 0; ks < 4; ++ks)
#pragma unroll
        for (int r = 0; r < 4; ++r) p[ks][r] = EXP2R(s[ks][r] - d);
    } else {
#pragma unroll
      for (int ks = 0; ks < 4; ++ks)
#pragma unroll
        for (int r = 0; r < 4; ++r) p[ks][r] = EXP2R(s[ks][r]);
    }

#pragma unroll
    for (int pi = 0; pi < 2; ++pi) {
      union { unsigned int u[4]; bf16x8 v; } bP;
      bP.u[0] = pk2(p[2 * pi][0], p[2 * pi][1]);
      bP.u[1] = pk2(p[2 * pi][2], p[2 * pi][3]);
      bP.u[2] = pk2(p[2 * pi + 1][0], p[2 * pi + 1][1]);
      bP.u[3] = pk2(p[2 * pi + 1][2], p[2 * pi + 1][3]);
      lsum = __builtin_amdgcn_mfma_f32_16x16x32_bf16(ones, bP.v, lsum, 0, 0, 0);
#pragma unroll
      for (int dt = 0; dt < 2; ++dt) {
        bf16x8 aV = *(const bf16x8*)&Vt[cur][(dt << 4) + l15][(pi << 5) + (g << 3)];
        opv[dt] = __builtin_amdgcn_mfma_f32_16x16x32_bf16(aV, bP.v, opv[dt], 0, 0, 0);
      }
    }

    if (kt < 63) {
      *(ushort8*)&Ks[cur ^ 1][krow][kd0] = kreg;
      ushort4v lo = {vreg[0], vreg[1], vreg[2], vreg[3]};
      ushort4v hi = {vreg[4], vreg[5], vreg[6], vreg[7]};
      *(ushort4v*)&Vt[cur ^ 1][vd][vpos] = lo;
      *(ushort4v*)&Vt[cur ^ 1][vd][vpos + 8] = hi;
    }
    __syncthreads();
  }

  // lsum rows are identical (ones matrix) -> per-lane l with no reduce
  float inv = 1.f / lsum[0];
  const int n = qt * 64 + (w << 4) + l15;
  unsigned short* aob = AO + (size_t)(b * 4096 + n) * 128 + (h << 5);
#pragma unroll
  for (int dt = 0; dt < 2; ++dt) {
    f32x4 o = opv[dt] * inv;
    ushort4v u = {f2bf(o[0]), f2bf(o[1]), f2bf(o[2]), f2bf(o[3])};
    *(ushort4v*)&aob[(dt << 4) + (g << 2)] = u;
  }
}

// proj + residual: X1[b,c,n] (f32) = x + AO.proj_w + proj_b
__global__ __launch_bounds__(256) void proj_kernel(const unsigned short* __restrict__ AO,
                                                   const unsigned short* __restrict__ Wp,
                                                   const float* __restrict__ bp,
                                                   const float* __restrict__ x,
                                                   float* __restrict__ X1) {
  const int row0 = blockIdx.x << 7, col0 = blockIdx.y << 6;
  f32x4 acc[2][4] = {};
  mfma_core<128>(AO, Wp, row0, col0, acc);
  const int t = threadIdx.x, w = t >> 6, lane = t & 63;
  const int l15 = lane & 15, g = lane >> 4;
#pragma unroll
  for (int mi = 0; mi < 2; ++mi) {
    int grow = row0 + (w << 5) + (mi << 4) + (g << 2);
    int b = grow >> 12, n0 = grow & 4095;
#pragma unroll
    for (int nj = 0; nj < 4; ++nj) {
      int c = col0 + (nj << 4) + l15;
      size_t idx = ((size_t)(b * C_ + c) << 12) + n0;
      f32x4 xv = *(const f32x4*)&x[idx];
      f32x4 r = xv + acc[mi][nj] + bp[c];
      *(f32x4*)&X1[idx] = r;
    }
  }
}

// fc1 + exact GELU -> H bf16 [16384, 256]
__global__ __launch_bounds__(256) void fc1_kernel(const unsigned short* __restrict__ XLN2,
                                                  const unsigned short* __restrict__ W1,
                                                  const float* __restrict__ b1,
                                                  unsigned short* __restrict__ Hb) {
  const int row0 = blockIdx.x << 7, col0 = blockIdx.y << 6;
  f32x4 acc[2][4] = {};
  mfma_core<128>(XLN2, W1, row0, col0, acc);
  const int t = threadIdx.x, w = t >> 6, lane = t & 63;
  const int l15 = lane & 15, g = lane >> 4;
#pragma unroll
  for (int mi = 0; mi < 2; ++mi) {
    int grow = row0 + (w << 5) + (mi << 4) + (g << 2);
#pragma unroll
    for (int nj = 0; nj < 4; ++nj) {
      int o = col0 + (nj << 4) + l15;
      float bb = b1[o];
#pragma unroll
      for (int r = 0; r < 4; ++r) {
        float v = acc[mi][nj][r] + bb;
        v = 0.5f * v * (1.f + erff(v * 0.70710678118654752f));
        Hb[(size_t)(grow + r) * 256 + o] = f2bf(v);
      }
    }
  }
}

// fc2 + residual -> out f32 NCHW
__global__ __launch_bounds__(256) void fc2_kernel(const unsigned short* __restrict__ Hb,
                                                  const unsigned short* __restrict__ W2,
                                                  const float* __restrict__ b2,
                                                  const float* __restrict__ X1,
                                                  float* __restrict__ outp) {
  const int row0 = blockIdx.x << 7, col0 = blockIdx.y << 6;
  f32x4 acc[2][4] = {};
  mfma_core<256>(Hb, W2, row0, col0, acc);
  const int t = threadIdx.x, w = t >> 6, lane = t & 63;
  const int l15 = lane & 15, g = lane >> 4;
#pragma unroll
  for (int mi = 0; mi < 2; ++mi) {
    int grow = row0 + (w << 5) + (mi << 4) + (g << 2);
    int b = grow >> 12, n0 = grow & 4095;
#pragma unroll
    for (int nj = 0; nj < 4; ++nj) {
      int c = col0 + (nj << 4) + l15;
      size_t idx = ((size_t)(b * C_ + c) << 12) + n0;
      f32x4 xv = *(const f32x4*)&X1[idx];
      f32x4 r = xv + acc[mi][nj] + b2[c];
      *(f32x4*)&outp[idx] = r;
    }
  }
}

extern "C" void kernel_launch(void* const* d_in, const int* in_sizes, int n_in,
                              void* d_out, int out_size, void* d_ws, size_t ws_size,
                              hipStream_t stream) {
  (void)in_sizes; (void)n_in; (void)out_size; (void)ws_size;
  const float* x     = (const float*)d_in[0];
  const float* ln1w  = (const float*)d_in[1];
  const float* ln1b  = (const float*)d_in[2];
  const float* qkvw  = (const float*)d_in[3];
  const float* projw = (const float*)d_in[4];
  const float* projb = (const float*)d_in[5];
  const float* ln2w  = (const float*)d_in[6];
  const float* ln2b  = (const float*)d_in[7];
  const float* fc1w  = (const float*)d_in[8];
  const float* fc1b  = (const float*)d_in[9];
  const float* fc2w  = (const float*)d_in[10];
  const float* fc2b  = (const float*)d_in[11];
  float* out = (float*)d_out;
  char* ws8 = (char*)d_ws;

  const size_t MB = 1u << 20;
  unsigned short* WB   = (unsigned short*)(ws8);            // 256 KB used
  unsigned short* XLN  = (unsigned short*)(ws8 + 1 * MB);   // 4 MB, reused as AO
  unsigned short* Qb   = (unsigned short*)(ws8 + 5 * MB);   // 4 MB, reused as XLN2
  unsigned short* Kb   = (unsigned short*)(ws8 + 9 * MB);   // 4 MB
  unsigned short* Vb   = (unsigned short*)(ws8 + 13 * MB);  // 4 MB
  unsigned short* AObf = XLN;                               // after qkv
  unsigned short* XLN2 = Qb;                                // after attn
  unsigned short* HB   = Kb;                                // 8 MB (K+V), after attn
  float*          X1   = (float*)(ws8 + 17 * MB);           // 8 MB
  const unsigned short* Wqkv = WB;
  const unsigned short* Wproj = WB + 49152;
  const unsigned short* Wfc1 = WB + 65536;
  const unsigned short* Wfc2 = WB + 98304;

  wconv_kernel<<<dim3(512), dim3(256), 0, stream>>>(qkvw, projw, fc1w, fc2w, WB);
  ln_kernel<<<dim3(256), dim3(256), 0, stream>>>(x, ln1w, ln1b, XLN);
  qkv_kernel<<<dim3(128, 6), dim3(256), 0, stream>>>(XLN, Wqkv, Qb, Kb, Vb);
  attn_kernel<<<dim3(1024), dim3(256), 0, stream>>>(Qb, Kb, Vb, AObf);
  proj_kernel<<<dim3(128, 2), dim3(256), 0, stream>>>(AObf, Wproj, projb, x, X1);
  ln_kernel<<<dim3(256), dim3(256), 0, stream>>>(X1, ln2w, ln2b, XLN2);
  fc1_kernel<<<dim3(128, 4), dim3(256), 0, stream>>>(XLN2, Wfc1, fc1b, HB);
  fc2_kernel<<<dim3(128, 2), dim3(256), 0, stream>>>(HB, Wfc2, fc2b, X1, out);
}

// Round 13
// 197.633 us; speedup vs baseline: 2.0395x; 1.0403x over previous
//
#include <hip/hip_runtime.h>
#include <hip/hip_bf16.h>

// ---------------------------------------------------------------------------
// MHSA + MLP block, B=4 C=128 H=W=64 (N=4096), HEADS=4 HD=32, HIDDEN=256.
// All GEMMs bf16 MFMA (16x16x32), activations bf16, residual spine fp32.
// Attn: swapped-operand flash, C-operand max-fold, defer-max (THR=8),
//       MFMA-ones l-sum, raw v_exp_f32, kt-loop unrolled x2 so LDS
//       double-buffer bases are compile-time constants (no runtime indexing).
// ws layout (bytes): WB bf16 weights [0,1M), XLN/AO bf16 [1M,5M),
//   Qb/XLN2 [5M,9M), Kb [9M,13M), Vb [13M,17M), H bf16 [9M,17M) after attn,
//   X1 f32 [17M,25M).  Total 25 MB.
// ---------------------------------------------------------------------------

typedef __attribute__((ext_vector_type(4))) float f32x4;
typedef __attribute__((ext_vector_type(8))) short bf16x8;       // MFMA A/B frag
typedef __attribute__((ext_vector_type(8))) unsigned short ushort8;
typedef __attribute__((ext_vector_type(4))) unsigned short ushort4v;

#define C_ 128
#define N_ 4096
#define SL2E 0.25504712280087033f   // (1/sqrt(32)) * log2(e)
#define EXP2R(x) __builtin_amdgcn_exp2f(x)   // bare v_exp_f32, no OCML guard

__device__ inline unsigned short f2bf(float f) {   // fp32 -> bf16 RNE
  unsigned int x = __float_as_uint(f);
  x += 0x7fffu + ((x >> 16) & 1u);
  return (unsigned short)(x >> 16);
}

__device__ inline unsigned int pk2(float a, float b) {  // pack 2xbf16 word
  __hip_bfloat162 h2 = __float22bfloat162_rn(make_float2(a, b));
  return *(unsigned int*)&h2;
}

// Weight conversion: qkv_w(49152) | proj_w(16384) | fc1_w(32768) | fc2_w(32768)
__global__ __launch_bounds__(256) void wconv_kernel(const float* __restrict__ qkvw,
                                                    const float* __restrict__ projw,
                                                    const float* __restrict__ fc1w,
                                                    const float* __restrict__ fc2w,
                                                    unsigned short* __restrict__ WB) {
  int i = blockIdx.x * 256 + threadIdx.x;       // grid 512 -> 131072
  float v;
  if (i < 49152) v = qkvw[i];
  else if (i < 65536) v = projw[i - 49152];
  else if (i < 98304) v = fc1w[i - 65536];
  else v = fc2w[i - 98304];
  WB[i] = f2bf(v);
}

// ---------------------------------------------------------------------------
// LayerNorm over channels. Input [B,C,N] (NCHW) f32, output rows [B*N, C] bf16.
// 32-position tiles (grid 512 = 2 blocks/CU, 8 waves/CU for latency hiding).
// ---------------------------------------------------------------------------
__global__ __launch_bounds__(256) void ln_kernel(const float* __restrict__ xin,
                                                 const float* __restrict__ gamma,
                                                 const float* __restrict__ beta,
                                                 unsigned short* __restrict__ outp) {
  __shared__ float tile[128][33];
  __shared__ float ps[8][32];
  __shared__ float pss[8][32];
  __shared__ float mu_s[32];
  __shared__ float rs_s[32];
  const int t = threadIdx.x;
  const int b = blockIdx.x >> 7;
  const int n0 = (blockIdx.x & 127) << 5;
  const float* xb = xin + (size_t)b * C_ * N_ + n0;
#pragma unroll
  for (int i = 0; i < 16; ++i) {
    int lin = i * 256 + t;
    int c = lin >> 5, p = lin & 31;
    tile[c][p] = xb[(size_t)c * N_ + p];
  }
  __syncthreads();
  {
    int p = t & 31, part = t >> 5;            // 8 parts x 16 channels
    float s = 0.f, ss = 0.f;
#pragma unroll
    for (int j = 0; j < 16; ++j) {
      float v = tile[part * 16 + j][p];
      s += v; ss += v * v;
    }
    ps[part][p] = s; pss[part][p] = ss;
  }
  __syncthreads();
  if (t < 32) {
    float su = 0.f, sq = 0.f;
#pragma unroll
    for (int k = 0; k < 8; ++k) { su += ps[k][t]; sq += pss[k][t]; }
    float mu = su * (1.f / 128.f);
    float var = sq * (1.f / 128.f) - mu * mu;
    mu_s[t] = mu;
    rs_s[t] = rsqrtf(var + 1e-5f);
  }
  __syncthreads();
  unsigned short* ob = outp + (size_t)(b * N_ + n0) * C_;
#pragma unroll
  for (int i = 0; i < 8; ++i) {             // 32 pos x 128 ch, 2 ch per thread
    int lin = i * 256 + t;
    int p = lin >> 6, c2 = (lin & 63) << 1;
    float mu = mu_s[p], rs = rs_s[p];
    float a = (tile[c2][p] - mu) * rs * gamma[c2] + beta[c2];
    float d = (tile[c2 + 1][p] - mu) * rs * gamma[c2 + 1] + beta[c2 + 1];
    *(unsigned int*)&ob[(size_t)p * C_ + c2] = pk2(a, d);
  }
}

// ---------------------------------------------------------------------------
// bf16 MFMA GEMM core (128x64 tile, XOR-swizzled LDS, 4 waves).
// ---------------------------------------------------------------------------
template <int KD>
__device__ inline void mfma_core(const unsigned short* __restrict__ A,
                                 const unsigned short* __restrict__ W,
                                 int row0, int col0, f32x4 acc[2][4]) {
  __shared__ __align__(16) unsigned short As[128][128];
  __shared__ __align__(16) unsigned short Ws[64][128];
  const int t = threadIdx.x;
  const int w = t >> 6, lane = t & 63;
  const int l15 = lane & 15, g = lane >> 4;
  const int srow = t >> 4, schunk = t & 15;    // staging: 16 thr cover one row
#pragma unroll
  for (int kt = 0; kt < KD / 128; ++kt) {
    __syncthreads();
#pragma unroll
    for (int i = 0; i < 8; ++i) {              // A tile 128x128
      int row = i * 16 + srow;
      int c = schunk ^ (row & 7);
      *(ushort8*)&As[row][c * 8] =
          *(const ushort8*)&A[(size_t)(row0 + row) * KD + kt * 128 + schunk * 8];
    }
#pragma unroll
    for (int i = 0; i < 4; ++i) {              // W tile 64x128
      int row = i * 16 + srow;
      int c = schunk ^ (row & 7);
      *(ushort8*)&Ws[row][c * 8] =
          *(const ushort8*)&W[(size_t)(col0 + row) * KD + kt * 128 + schunk * 8];
    }
    __syncthreads();
#pragma unroll
    for (int kk = 0; kk < 4; ++kk) {
      bf16x8 aA[2], bW[4];
#pragma unroll
      for (int mi = 0; mi < 2; ++mi) {
        int mrow = (w << 5) + (mi << 4) + l15;
        int c = (kk * 4 + g) ^ (mrow & 7);
        aA[mi] = *(const bf16x8*)&As[mrow][c * 8];
      }
#pragma unroll
      for (int nj = 0; nj < 4; ++nj) {
        int wrow = (nj << 4) + l15;
        int c = (kk * 4 + g) ^ (wrow & 7);
        bW[nj] = *(const bf16x8*)&Ws[wrow][c * 8];
      }
#pragma unroll
      for (int mi = 0; mi < 2; ++mi)
#pragma unroll
        for (int nj = 0; nj < 4; ++nj)
          acc[mi][nj] = __builtin_amdgcn_mfma_f32_16x16x32_bf16(aA[mi], bW[nj],
                                                                acc[mi][nj], 0, 0, 0);
    }
  }
}

// QKV: XLN [16384,128] x WB[384,128] -> bf16 Q,K [bh][n][32], V [bh][32][n].
__global__ __launch_bounds__(256) void qkv_kernel(const unsigned short* __restrict__ XLN,
                                                  const unsigned short* __restrict__ Wq,
                                                  unsigned short* __restrict__ Qb,
                                                  unsigned short* __restrict__ Kb,
                                                  unsigned short* __restrict__ Vb) {
  const int row0 = blockIdx.x << 7, col0 = blockIdx.y << 6;
  f32x4 acc[2][4] = {};
  mfma_core<128>(XLN, Wq, row0, col0, acc);
  const int t = threadIdx.x, w = t >> 6, lane = t & 63;
  const int l15 = lane & 15, g = lane >> 4;
#pragma unroll
  for (int mi = 0; mi < 2; ++mi) {
    int grow = row0 + (w << 5) + (mi << 4) + (g << 2);
    int b = grow >> 12, n0 = grow & 4095;
#pragma unroll
    for (int nj = 0; nj < 4; ++nj) {
      int o = col0 + (nj << 4) + l15;
      int ch = o & 127, hh = ch >> 5, d = ch & 31;
      f32x4 a = acc[mi][nj];
      if (o < 128) {
        size_t base = ((size_t)(b * 4 + hh) * 4096 + n0) * 32 + d;
#pragma unroll
        for (int r = 0; r < 4; ++r) Qb[base + (size_t)r * 32] = f2bf(a[r] * SL2E);
      } else if (o < 256) {
        size_t base = ((size_t)(b * 4 + hh) * 4096 + n0) * 32 + d;
#pragma unroll
        for (int r = 0; r < 4; ++r) Kb[base + (size_t)r * 32] = f2bf(a[r]);
      } else {
        ushort4v u = {f2bf(a[0]), f2bf(a[1]), f2bf(a[2]), f2bf(a[3])};
        *(ushort4v*)&Vb[((size_t)(b * 4 + hh) * 32 + d) * 4096 + n0] = u;
      }
    }
  }
}

// ---------------------------------------------------------------------------
// Flash attention. One chunk body with COMPILE-TIME buffer index CUR:
// all Ks/Vt addresses are loop-invariant base + immediate offset.
// ---------------------------------------------------------------------------
#define ATTN_CHUNK(CUR, KT)                                                     \
  {                                                                             \
    if ((KT) < 63) {                                                            \
      kreg = *(const ushort8*)kp_n;  kp_n += 64 * 32;                           \
      vreg = *(const ushort8*)vp_n;  vp_n += 64;                                \
    }                                                                           \
    f32x4 s[4];                                                                 \
    _Pragma("unroll")                                                           \
    for (int ks = 0; ks < 4; ++ks) {                                            \
      bf16x8 bK = *(const bf16x8*)&Ks[CUR][(ks << 4) + l15][g << 3];            \
      s[ks] = __builtin_amdgcn_mfma_f32_16x16x32_bf16(bK, aQ, cneg, 0, 0, 0);   \
    }                                                                           \
    float a0 = fmaxf(fmaxf(s[0][0], s[0][1]), s[0][2]);                         \
    float a1 = fmaxf(fmaxf(s[0][3], s[1][0]), s[1][1]);                         \
    float a2 = fmaxf(fmaxf(s[1][2], s[1][3]), s[2][0]);                         \
    float a3 = fmaxf(fmaxf(s[2][1], s[2][2]), s[2][3]);                         \
    float a4 = fmaxf(fmaxf(s[3][0], s[3][1]), s[3][2]);                         \
    float m0 = fmaxf(fmaxf(fmaxf(a0, a1), fmaxf(a2, a3)), fmaxf(a4, s[3][3]));  \
    float p[4][4];                                                              \
    if (__builtin_expect(!__all(m0 <= 8.f), 0)) {                               \
      m0 = fmaxf(m0, __shfl_xor(m0, 16));                                       \
      m0 = fmaxf(m0, __shfl_xor(m0, 32));                                       \
      float d = fmaxf(m0, 0.f);                                                 \
      float al = EXP2R(-d);                                                     \
      m_r += d;                                                                 \
      cneg = zero - m_r;                                                        \
      opv[0] *= al;  opv[1] *= al;  lsum *= al;                                 \
      _Pragma("unroll")                                                         \
      for (int ks = 0; ks < 4; ++ks)                                            \
        _Pragma("unroll")                                                       \
        for (int r = 0; r < 4; ++r) p[ks][r] = EXP2R(s[ks][r] - d);             \
    } else {                                                                    \
      _Pragma("unroll")                                                         \
      for (int ks = 0; ks < 4; ++ks)                                            \
        _Pragma("unroll")                                                       \
        for (int r = 0; r < 4; ++r) p[ks][r] = EXP2R(s[ks][r]);                 \
    }                                                                           \
    _Pragma("unroll")                                                           \
    for (int pi = 0; pi < 2; ++pi) {                                            \
      union { unsigned int u[4]; bf16x8 v; } bP;                                \
      bP.u[0] = pk2(p[2 * pi][0], p[2 * pi][1]);                                \
      bP.u[1] = pk2(p[2 * pi][2], p[2 * pi][3]);                                \
      bP.u[2] = pk2(p[2 * pi + 1][0], p[2 * pi + 1][1]);                        \
      bP.u[3] = pk2(p[2 * pi + 1][2], p[2 * pi + 1][3]);                        \
      lsum = __builtin_amdgcn_mfma_f32_16x16x32_bf16(ones, bP.v, lsum, 0, 0, 0);\
      _Pragma("unroll")                                                         \
      for (int dt = 0; dt < 2; ++dt) {                                          \
        bf16x8 aV =                                                             \
            *(const bf16x8*)&Vt[CUR][(dt << 4) + l15][(pi << 5) + (g << 3)];    \
        opv[dt] = __builtin_amdgcn_mfma_f32_16x16x32_bf16(aV, bP.v, opv[dt],    \
                                                          0, 0, 0);             \
      }                                                                         \
    }                                                                           \
    if ((KT) < 63) {                                                            \
      *(ushort8*)&Ks[(CUR) ^ 1][krow][kd0] = kreg;                              \
      ushort4v lo = {vreg[0], vreg[1], vreg[2], vreg[3]};                       \
      ushort4v hi = {vreg[4], vreg[5], vreg[6], vreg[7]};                       \
      *(ushort4v*)&Vt[(CUR) ^ 1][vd][vpos] = lo;                                \
      *(ushort4v*)&Vt[(CUR) ^ 1][vd][vpos + 8] = hi;                            \
    }                                                                           \
    __syncthreads();                                                            \
  }

__global__ __launch_bounds__(256) void attn_kernel(const unsigned short* __restrict__ Qg,
                                                   const unsigned short* __restrict__ Kg,
                                                   const unsigned short* __restrict__ Vg,
                                                   unsigned short* __restrict__ AO) {
  __shared__ __align__(16) unsigned short Qa[64][40];
  __shared__ __align__(16) unsigned short Ks[2][64][40];
  __shared__ __align__(16) unsigned short Vt[2][32][72];
  const int id = blockIdx.x;                     // grid 1024
  const int bh = (id & 7) | ((id >> 9) << 3);    // xcd = bh % 8 (K/V L2-resident)
  const int qt = (id >> 3) & 63;
  const int b = bh >> 2, h = bh & 3;
  const unsigned short* Qp = Qg + ((size_t)bh * 4096 + qt * 64) * 32;
  const unsigned short* Kp = Kg + (size_t)bh * 4096 * 32;
  const unsigned short* Vp = Vg + (size_t)bh * 32 * 4096;
  const int t = threadIdx.x;
  const int lane = t & 63, w = t >> 6;
  const int l15 = lane & 15, g = lane >> 4;
  const int krow = t >> 2, kd0 = (t & 3) << 3;   // K/Q staging coords
  const int vd = t >> 3, vc = t & 7;             // V staging: row, key-octet
  const int vpos = ((vc >> 2) << 5) + ((vc & 1) << 4) + (((vc & 3) >> 1) << 2);

  *(ushort8*)&Qa[krow][kd0] = *(const ushort8*)(Qp + krow * 32 + kd0);
  ushort8 kreg = *(const ushort8*)(Kp + (size_t)krow * 32 + kd0);
  ushort8 vreg = *(const ushort8*)(Vp + (size_t)vd * 4096 + (vc << 3));
  const unsigned short* kp_n = Kp + 64 * 32 + (size_t)krow * 32 + kd0;
  const unsigned short* vp_n = Vp + (size_t)vd * 4096 + 64 + (vc << 3);
  *(ushort8*)&Ks[0][krow][kd0] = kreg;
  {
    ushort4v lo = {vreg[0], vreg[1], vreg[2], vreg[3]};
    ushort4v hi = {vreg[4], vreg[5], vreg[6], vreg[7]};
    *(ushort4v*)&Vt[0][vd][vpos] = lo;
    *(ushort4v*)&Vt[0][vd][vpos + 8] = hi;
  }
  __syncthreads();
  const bf16x8 aQ = *(const bf16x8*)&Qa[(w << 4) + l15][g << 3];
  const short oneb = (short)0x3F80;              // bf16 1.0
  const bf16x8 ones = {oneb, oneb, oneb, oneb, oneb, oneb, oneb, oneb};

  const f32x4 zero = {0.f, 0.f, 0.f, 0.f};
  f32x4 opv[2]; opv[0] = zero; opv[1] = zero;
  f32x4 lsum = zero;
  f32x4 cneg = zero;                             // splat(-m_r)
  float m_r = 0.f;

  for (int kt2 = 0; kt2 < 64; kt2 += 2) {        // unrolled x2: CUR is literal
    ATTN_CHUNK(0, kt2);
    ATTN_CHUNK(1, kt2 + 1);
  }

  // lsum rows are identical (ones matrix) -> per-lane l with no reduce
  float inv = 1.f / lsum[0];
  const int n = qt * 64 + (w << 4) + l15;
  unsigned short* aob = AO + (size_t)(b * 4096 + n) * 128 + (h << 5);
#pragma unroll
  for (int dt = 0; dt < 2; ++dt) {
    f32x4 o = opv[dt] * inv;
    ushort4v u = {f2bf(o[0]), f2bf(o[1]), f2bf(o[2]), f2bf(o[3])};
    *(ushort4v*)&aob[(dt << 4) + (g << 2)] = u;
  }
}

// proj + residual: X1[b,c,n] (f32) = x + AO.proj_w + proj_b
__global__ __launch_bounds__(256) void proj_kernel(const unsigned short* __restrict__ AO,
                                                   const unsigned short* __restrict__ Wp,
                                                   const float* __restrict__ bp,
                                                   const float* __restrict__ x,
                                                   float* __restrict__ X1) {
  const int row0 = blockIdx.x << 7, col0 = blockIdx.y << 6;
  f32x4 acc[2][4] = {};
  mfma_core<128>(AO, Wp, row0, col0, acc);
  const int t = threadIdx.x, w = t >> 6, lane = t & 63;
  const int l15 = lane & 15, g = lane >> 4;
#pragma unroll
  for (int mi = 0; mi < 2; ++mi) {
    int grow = row0 + (w << 5) + (mi << 4) + (g << 2);
    int b = grow >> 12, n0 = grow & 4095;
#pragma unroll
    for (int nj = 0; nj < 4; ++nj) {
      int c = col0 + (nj << 4) + l15;
      size_t idx = ((size_t)(b * C_ + c) << 12) + n0;
      f32x4 xv = *(const f32x4*)&x[idx];
      f32x4 r = xv + acc[mi][nj] + bp[c];
      *(f32x4*)&X1[idx] = r;
    }
  }
}

// fc1 + exact GELU -> H bf16 [16384, 256]
__global__ __launch_bounds__(256) void fc1_kernel(const unsigned short* __restrict__ XLN2,
                                                  const unsigned short* __restrict__ W1,
                                                  const float* __restrict__ b1,
                                                  unsigned short* __restrict__ Hb) {
  const int row0 = blockIdx.x << 7, col0 = blockIdx.y << 6;
  f32x4 acc[2][4] = {};
  mfma_core<128>(XLN2, W1, row0, col0, acc);
  const int t = threadIdx.x, w = t >> 6, lane = t & 63;
  const int l15 = lane & 15, g = lane >> 4;
#pragma unroll
  for (int mi = 0; mi < 2; ++mi) {
    int grow = row0 + (w << 5) + (mi << 4) + (g << 2);
#pragma unroll
    for (int nj = 0; nj < 4; ++nj) {
      int o = col0 + (nj << 4) + l15;
      float bb = b1[o];
#pragma unroll
      for (int r = 0; r < 4; ++r) {
        float v = acc[mi][nj][r] + bb;
        v = 0.5f * v * (1.f + erff(v * 0.70710678118654752f));
        Hb[(size_t)(grow + r) * 256 + o] = f2bf(v);
      }
    }
  }
}

// fc2 + residual -> out f32 NCHW
__global__ __launch_bounds__(256) void fc2_kernel(const unsigned short* __restrict__ Hb,
                                                  const unsigned short* __restrict__ W2,
                                                  const float* __restrict__ b2,
                                                  const float* __restrict__ X1,
                                                  float* __restrict__ outp) {
  const int row0 = blockIdx.x << 7, col0 = blockIdx.y << 6;
  f32x4 acc[2][4] = {};
  mfma_core<256>(Hb, W2, row0, col0, acc);
  const int t = threadIdx.x, w = t >> 6, lane = t & 63;
  const int l15 = lane & 15, g = lane >> 4;
#pragma unroll
  for (int mi = 0; mi < 2; ++mi) {
    int grow = row0 + (w << 5) + (mi << 4) + (g << 2);
    int b = grow >> 12, n0 = grow & 4095;
#pragma unroll
    for (int nj = 0; nj < 4; ++nj) {
      int c = col0 + (nj << 4) + l15;
      size_t idx = ((size_t)(b * C_ + c) << 12) + n0;
      f32x4 xv = *(const f32x4*)&X1[idx];
      f32x4 r = xv + acc[mi][nj] + b2[c];
      *(f32x4*)&outp[idx] = r;
    }
  }
}

extern "C" void kernel_launch(void* const* d_in, const int* in_sizes, int n_in,
                              void* d_out, int out_size, void* d_ws, size_t ws_size,
                              hipStream_t stream) {
  (void)in_sizes; (void)n_in; (void)out_size; (void)ws_size;
  const float* x     = (const float*)d_in[0];
  const float* ln1w  = (const float*)d_in[1];
  const float* ln1b  = (const float*)d_in[2];
  const float* qkvw  = (const float*)d_in[3];
  const float* projw = (const float*)d_in[4];
  const float* projb = (const float*)d_in[5];
  const float* ln2w  = (const float*)d_in[6];
  const float* ln2b  = (const float*)d_in[7];
  const float* fc1w  = (const float*)d_in[8];
  const float* fc1b  = (const float*)d_in[9];
  const float* fc2w  = (const float*)d_in[10];
  const float* fc2b  = (const float*)d_in[11];
  float* out = (float*)d_out;
  char* ws8 = (char*)d_ws;

  const size_t MB = 1u << 20;
  unsigned short* WB   = (unsigned short*)(ws8);            // 256 KB used
  unsigned short* XLN  = (unsigned short*)(ws8 + 1 * MB);   // 4 MB, reused as AO
  unsigned short* Qb   = (unsigned short*)(ws8 + 5 * MB);   // 4 MB, reused as XLN2
  unsigned short* Kb   = (unsigned short*)(ws8 + 9 * MB);   // 4 MB
  unsigned short* Vb   = (unsigned short*)(ws8 + 13 * MB);  // 4 MB
  unsigned short* AObf = XLN;                               // after qkv
  unsigned short* XLN2 = Qb;                                // after attn
  unsigned short* HB   = Kb;                                // 8 MB (K+V), after attn
  float*          X1   = (float*)(ws8 + 17 * MB);           // 8 MB
  const unsigned short* Wqkv = WB;
  const unsigned short* Wproj = WB + 49152;
  const unsigned short* Wfc1 = WB + 65536;
  const unsigned short* Wfc2 = WB + 98304;

  wconv_kernel<<<dim3(512), dim3(256), 0, stream>>>(qkvw, projw, fc1w, fc2w, WB);
  ln_kernel<<<dim3(512), dim3(256), 0, stream>>>(x, ln1w, ln1b, XLN);
  qkv_kernel<<<dim3(128, 6), dim3(256), 0, stream>>>(XLN, Wqkv, Qb, Kb, Vb);
  attn_kernel<<<dim3(1024), dim3(256), 0, stream>>>(Qb, Kb, Vb, AObf);
  proj_kernel<<<dim3(128, 2), dim3(256), 0, stream>>>(AObf, Wproj, projb, x, X1);
  ln_kernel<<<dim3(512), dim3(256), 0, stream>>>(X1, ln2w, ln2b, XLN2);
  fc1_kernel<<<dim3(128, 4), dim3(256), 0, stream>>>(XLN2, Wfc1, fc1b, HB);
  fc2_kernel<<<dim3(128, 2), dim3(256), 0, stream>>>(HB, Wfc2, fc2b, X1, out);
}

// Round 14
// 185.486 us; speedup vs baseline: 2.1731x; 1.0655x over previous
//
#include <hip/hip_runtime.h>
#include <hip/hip_bf16.h>

// ---------------------------------------------------------------------------
// MHSA + MLP block, B=4 C=128 H=W=64 (N=4096), HEADS=4 HD=32, HIDDEN=256.
// All GEMMs bf16 MFMA (16x16x32), activations bf16, residual spine fp32.
// Attn: swapped-operand flash, C-operand max-fold, defer-max (THR=8),
//       MFMA-ones l-sum, raw v_exp_f32, const-CUR unroll, asm v_cvt_pk_bf16.
// proj+LN2 fused: X1 = x + AO.Wp + bp, then in-register LN -> XLN2.
// ws layout (bytes): WB bf16 weights [0,1M), XLN/AO bf16 [1M,5M),
//   Qb/XLN2 [5M,9M), Kb [9M,13M), Vb [13M,17M), H bf16 [9M,17M) after attn,
//   X1 f32 [17M,25M).  Total 25 MB.
// ---------------------------------------------------------------------------

typedef __attribute__((ext_vector_type(4))) float f32x4;
typedef __attribute__((ext_vector_type(8))) short bf16x8;       // MFMA A/B frag
typedef __attribute__((ext_vector_type(8))) unsigned short ushort8;
typedef __attribute__((ext_vector_type(4))) unsigned short ushort4v;

#define C_ 128
#define N_ 4096
#define SL2E 0.25504712280087033f   // (1/sqrt(32)) * log2(e)
#define EXP2R(x) __builtin_amdgcn_exp2f(x)   // bare v_exp_f32, no OCML guard

__device__ inline unsigned short f2bf(float f) {   // fp32 -> bf16 RNE
  unsigned int x = __float_as_uint(f);
  x += 0x7fffu + ((x >> 16) & 1u);
  return (unsigned short)(x >> 16);
}

__device__ inline unsigned int pk2(float a, float b) {  // 2xf32 -> packed bf16x2
  unsigned int r;
  asm("v_cvt_pk_bf16_f32 %0, %1, %2" : "=v"(r) : "v"(a), "v"(b));
  return r;
}

// Weight conversion: qkv_w(49152) | proj_w(16384) | fc1_w(32768) | fc2_w(32768)
__global__ __launch_bounds__(256) void wconv_kernel(const float* __restrict__ qkvw,
                                                    const float* __restrict__ projw,
                                                    const float* __restrict__ fc1w,
                                                    const float* __restrict__ fc2w,
                                                    unsigned short* __restrict__ WB) {
  int i = blockIdx.x * 256 + threadIdx.x;       // grid 512 -> 131072
  float v;
  if (i < 49152) v = qkvw[i];
  else if (i < 65536) v = projw[i - 49152];
  else if (i < 98304) v = fc1w[i - 65536];
  else v = fc2w[i - 98304];
  WB[i] = f2bf(v);
}

// ---------------------------------------------------------------------------
// LayerNorm over channels (LN1). Input [B,C,N] f32, out rows [B*N, C] bf16.
// 32-position tiles (grid 512).
// ---------------------------------------------------------------------------
__global__ __launch_bounds__(256) void ln_kernel(const float* __restrict__ xin,
                                                 const float* __restrict__ gamma,
                                                 const float* __restrict__ beta,
                                                 unsigned short* __restrict__ outp) {
  __shared__ float tile[128][33];
  __shared__ float ps[8][32];
  __shared__ float pss[8][32];
  __shared__ float mu_s[32];
  __shared__ float rs_s[32];
  const int t = threadIdx.x;
  const int b = blockIdx.x >> 7;
  const int n0 = (blockIdx.x & 127) << 5;
  const float* xb = xin + (size_t)b * C_ * N_ + n0;
#pragma unroll
  for (int i = 0; i < 16; ++i) {
    int lin = i * 256 + t;
    int c = lin >> 5, p = lin & 31;
    tile[c][p] = xb[(size_t)c * N_ + p];
  }
  __syncthreads();
  {
    int p = t & 31, part = t >> 5;            // 8 parts x 16 channels
    float s = 0.f, ss = 0.f;
#pragma unroll
    for (int j = 0; j < 16; ++j) {
      float v = tile[part * 16 + j][p];
      s += v; ss += v * v;
    }
    ps[part][p] = s; pss[part][p] = ss;
  }
  __syncthreads();
  if (t < 32) {
    float su = 0.f, sq = 0.f;
#pragma unroll
    for (int k = 0; k < 8; ++k) { su += ps[k][t]; sq += pss[k][t]; }
    float mu = su * (1.f / 128.f);
    float var = sq * (1.f / 128.f) - mu * mu;
    mu_s[t] = mu;
    rs_s[t] = rsqrtf(var + 1e-5f);
  }
  __syncthreads();
  unsigned short* ob = outp + (size_t)(b * N_ + n0) * C_;
#pragma unroll
  for (int i = 0; i < 8; ++i) {             // 32 pos x 128 ch, 2 ch per thread
    int lin = i * 256 + t;
    int p = lin >> 6, c2 = (lin & 63) << 1;
    float mu = mu_s[p], rs = rs_s[p];
    float a = (tile[c2][p] - mu) * rs * gamma[c2] + beta[c2];
    float d = (tile[c2 + 1][p] - mu) * rs * gamma[c2 + 1] + beta[c2 + 1];
    *(unsigned int*)&ob[(size_t)p * C_ + c2] = pk2(a, d);
  }
}

// ---------------------------------------------------------------------------
// bf16 MFMA GEMM core (128x64 tile, XOR-swizzled LDS, 4 waves).
// ---------------------------------------------------------------------------
template <int KD>
__device__ inline void mfma_core(const unsigned short* __restrict__ A,
                                 const unsigned short* __restrict__ W,
                                 int row0, int col0, f32x4 acc[2][4]) {
  __shared__ __align__(16) unsigned short As[128][128];
  __shared__ __align__(16) unsigned short Ws[64][128];
  const int t = threadIdx.x;
  const int w = t >> 6, lane = t & 63;
  const int l15 = lane & 15, g = lane >> 4;
  const int srow = t >> 4, schunk = t & 15;    // staging: 16 thr cover one row
#pragma unroll
  for (int kt = 0; kt < KD / 128; ++kt) {
    __syncthreads();
#pragma unroll
    for (int i = 0; i < 8; ++i) {              // A tile 128x128
      int row = i * 16 + srow;
      int c = schunk ^ (row & 7);
      *(ushort8*)&As[row][c * 8] =
          *(const ushort8*)&A[(size_t)(row0 + row) * KD + kt * 128 + schunk * 8];
    }
#pragma unroll
    for (int i = 0; i < 4; ++i) {              // W tile 64x128
      int row = i * 16 + srow;
      int c = schunk ^ (row & 7);
      *(ushort8*)&Ws[row][c * 8] =
          *(const ushort8*)&W[(size_t)(col0 + row) * KD + kt * 128 + schunk * 8];
    }
    __syncthreads();
#pragma unroll
    for (int kk = 0; kk < 4; ++kk) {
      bf16x8 aA[2], bW[4];
#pragma unroll
      for (int mi = 0; mi < 2; ++mi) {
        int mrow = (w << 5) + (mi << 4) + l15;
        int c = (kk * 4 + g) ^ (mrow & 7);
        aA[mi] = *(const bf16x8*)&As[mrow][c * 8];
      }
#pragma unroll
      for (int nj = 0; nj < 4; ++nj) {
        int wrow = (nj << 4) + l15;
        int c = (kk * 4 + g) ^ (wrow & 7);
        bW[nj] = *(const bf16x8*)&Ws[wrow][c * 8];
      }
#pragma unroll
      for (int mi = 0; mi < 2; ++mi)
#pragma unroll
        for (int nj = 0; nj < 4; ++nj)
          acc[mi][nj] = __builtin_amdgcn_mfma_f32_16x16x32_bf16(aA[mi], bW[nj],
                                                                acc[mi][nj], 0, 0, 0);
    }
  }
}

// QKV: XLN [16384,128] x WB[384,128] -> bf16 Q,K [bh][n][32], V [bh][32][n].
__global__ __launch_bounds__(256) void qkv_kernel(const unsigned short* __restrict__ XLN,
                                                  const unsigned short* __restrict__ Wq,
                                                  unsigned short* __restrict__ Qb,
                                                  unsigned short* __restrict__ Kb,
                                                  unsigned short* __restrict__ Vb) {
  const int row0 = blockIdx.x << 7, col0 = blockIdx.y << 6;
  f32x4 acc[2][4] = {};
  mfma_core<128>(XLN, Wq, row0, col0, acc);
  const int t = threadIdx.x, w = t >> 6, lane = t & 63;
  const int l15 = lane & 15, g = lane >> 4;
#pragma unroll
  for (int mi = 0; mi < 2; ++mi) {
    int grow = row0 + (w << 5) + (mi << 4) + (g << 2);
    int b = grow >> 12, n0 = grow & 4095;
#pragma unroll
    for (int nj = 0; nj < 4; ++nj) {
      int o = col0 + (nj << 4) + l15;
      int ch = o & 127, hh = ch >> 5, d = ch & 31;
      f32x4 a = acc[mi][nj];
      if (o < 128) {
        size_t base = ((size_t)(b * 4 + hh) * 4096 + n0) * 32 + d;
#pragma unroll
        for (int r = 0; r < 4; ++r) Qb[base + (size_t)r * 32] = f2bf(a[r] * SL2E);
      } else if (o < 256) {
        size_t base = ((size_t)(b * 4 + hh) * 4096 + n0) * 32 + d;
#pragma unroll
        for (int r = 0; r < 4; ++r) Kb[base + (size_t)r * 32] = f2bf(a[r]);
      } else {
        ushort4v u = {f2bf(a[0]), f2bf(a[1]), f2bf(a[2]), f2bf(a[3])};
        *(ushort4v*)&Vb[((size_t)(b * 4 + hh) * 32 + d) * 4096 + n0] = u;
      }
    }
  }
}

// ---------------------------------------------------------------------------
// Flash attention. One chunk body with COMPILE-TIME buffer index CUR.
// ---------------------------------------------------------------------------
#define ATTN_CHUNK(CUR, KT)                                                     \
  {                                                                             \
    if ((KT) < 63) {                                                            \
      kreg = *(const ushort8*)kp_n;  kp_n += 64 * 32;                           \
      vreg = *(const ushort8*)vp_n;  vp_n += 64;                                \
    }                                                                           \
    f32x4 s[4];                                                                 \
    _Pragma("unroll")                                                           \
    for (int ks = 0; ks < 4; ++ks) {                                            \
      bf16x8 bK = *(const bf16x8*)&Ks[CUR][(ks << 4) + l15][g << 3];            \
      s[ks] = __builtin_amdgcn_mfma_f32_16x16x32_bf16(bK, aQ, cneg, 0, 0, 0);   \
    }                                                                           \
    float a0 = fmaxf(fmaxf(s[0][0], s[0][1]), s[0][2]);                         \
    float a1 = fmaxf(fmaxf(s[0][3], s[1][0]), s[1][1]);                         \
    float a2 = fmaxf(fmaxf(s[1][2], s[1][3]), s[2][0]);                         \
    float a3 = fmaxf(fmaxf(s[2][1], s[2][2]), s[2][3]);                         \
    float a4 = fmaxf(fmaxf(s[3][0], s[3][1]), s[3][2]);                         \
    float m0 = fmaxf(fmaxf(fmaxf(a0, a1), fmaxf(a2, a3)), fmaxf(a4, s[3][3]));  \
    float p[4][4];                                                              \
    if (__builtin_expect(!__all(m0 <= 8.f), 0)) {                               \
      m0 = fmaxf(m0, __shfl_xor(m0, 16));                                       \
      m0 = fmaxf(m0, __shfl_xor(m0, 32));                                       \
      float d = fmaxf(m0, 0.f);                                                 \
      float al = EXP2R(-d);                                                     \
      m_r += d;                                                                 \
      cneg = zero - m_r;                                                        \
      opv[0] *= al;  opv[1] *= al;  lsum *= al;                                 \
      _Pragma("unroll")                                                         \
      for (int ks = 0; ks < 4; ++ks)                                            \
        _Pragma("unroll")                                                       \
        for (int r = 0; r < 4; ++r) p[ks][r] = EXP2R(s[ks][r] - d);             \
    } else {                                                                    \
      _Pragma("unroll")                                                         \
      for (int ks = 0; ks < 4; ++ks)                                            \
        _Pragma("unroll")                                                       \
        for (int r = 0; r < 4; ++r) p[ks][r] = EXP2R(s[ks][r]);                 \
    }                                                                           \
    _Pragma("unroll")                                                           \
    for (int pi = 0; pi < 2; ++pi) {                                            \
      union { unsigned int u[4]; bf16x8 v; } bP;                                \
      bP.u[0] = pk2(p[2 * pi][0], p[2 * pi][1]);                                \
      bP.u[1] = pk2(p[2 * pi][2], p[2 * pi][3]);                                \
      bP.u[2] = pk2(p[2 * pi + 1][0], p[2 * pi + 1][1]);                        \
      bP.u[3] = pk2(p[2 * pi + 1][2], p[2 * pi + 1][3]);                        \
      lsum = __builtin_amdgcn_mfma_f32_16x16x32_bf16(ones, bP.v, lsum, 0, 0, 0);\
      _Pragma("unroll")                                                         \
      for (int dt = 0; dt < 2; ++dt) {                                          \
        bf16x8 aV =                                                             \
            *(const bf16x8*)&Vt[CUR][(dt << 4) + l15][(pi << 5) + (g << 3)];    \
        opv[dt] = __builtin_amdgcn_mfma_f32_16x16x32_bf16(aV, bP.v, opv[dt],    \
                                                          0, 0, 0);             \
      }                                                                         \
    }                                                                           \
    if ((KT) < 63) {                                                            \
      *(ushort8*)&Ks[(CUR) ^ 1][krow][kd0] = kreg;                              \
      ushort4v lo = {vreg[0], vreg[1], vreg[2], vreg[3]};                       \
      ushort4v hi = {vreg[4], vreg[5], vreg[6], vreg[7]};                       \
      *(ushort4v*)&Vt[(CUR) ^ 1][vd][vpos] = lo;                                \
      *(ushort4v*)&Vt[(CUR) ^ 1][vd][vpos + 8] = hi;                            \
    }                                                                           \
    __syncthreads();                                                            \
  }

__global__ __launch_bounds__(256) void attn_kernel(const unsigned short* __restrict__ Qg,
                                                   const unsigned short* __restrict__ Kg,
                                                   const unsigned short* __restrict__ Vg,
                                                   unsigned short* __restrict__ AO) {
  __shared__ __align__(16) unsigned short Qa[64][40];
  __shared__ __align__(16) unsigned short Ks[2][64][40];
  __shared__ __align__(16) unsigned short Vt[2][32][72];
  const int id = blockIdx.x;                     // grid 1024
  const int bh = (id & 7) | ((id >> 9) << 3);    // xcd = bh % 8 (K/V L2-resident)
  const int qt = (id >> 3) & 63;
  const int b = bh >> 2, h = bh & 3;
  const unsigned short* Qp = Qg + ((size_t)bh * 4096 + qt * 64) * 32;
  const unsigned short* Kp = Kg + (size_t)bh * 4096 * 32;
  const unsigned short* Vp = Vg + (size_t)bh * 32 * 4096;
  const int t = threadIdx.x;
  const int lane = t & 63, w = t >> 6;
  const int l15 = lane & 15, g = lane >> 4;
  const int krow = t >> 2, kd0 = (t & 3) << 3;   // K/Q staging coords
  const int vd = t >> 3, vc = t & 7;             // V staging: row, key-octet
  const int vpos = ((vc >> 2) << 5) + ((vc & 1) << 4) + (((vc & 3) >> 1) << 2);

  *(ushort8*)&Qa[krow][kd0] = *(const ushort8*)(Qp + krow * 32 + kd0);
  ushort8 kreg = *(const ushort8*)(Kp + (size_t)krow * 32 + kd0);
  ushort8 vreg = *(const ushort8*)(Vp + (size_t)vd * 4096 + (vc << 3));
  const unsigned short* kp_n = Kp + 64 * 32 + (size_t)krow * 32 + kd0;
  const unsigned short* vp_n = Vp + (size_t)vd * 4096 + 64 + (vc << 3);
  *(ushort8*)&Ks[0][krow][kd0] = kreg;
  {
    ushort4v lo = {vreg[0], vreg[1], vreg[2], vreg[3]};
    ushort4v hi = {vreg[4], vreg[5], vreg[6], vreg[7]};
    *(ushort4v*)&Vt[0][vd][vpos] = lo;
    *(ushort4v*)&Vt[0][vd][vpos + 8] = hi;
  }
  __syncthreads();
  const bf16x8 aQ = *(const bf16x8*)&Qa[(w << 4) + l15][g << 3];
  const short oneb = (short)0x3F80;              // bf16 1.0
  const bf16x8 ones = {oneb, oneb, oneb, oneb, oneb, oneb, oneb, oneb};

  const f32x4 zero = {0.f, 0.f, 0.f, 0.f};
  f32x4 opv[2]; opv[0] = zero; opv[1] = zero;
  f32x4 lsum = zero;
  f32x4 cneg = zero;                             // splat(-m_r)
  float m_r = 0.f;

  for (int kt2 = 0; kt2 < 64; kt2 += 2) {        // unrolled x2: CUR is literal
    ATTN_CHUNK(0, kt2);
    ATTN_CHUNK(1, kt2 + 1);
  }

  // lsum rows are identical (ones matrix) -> per-lane l with no reduce
  float inv = 1.f / lsum[0];
  const int n = qt * 64 + (w << 4) + l15;
  unsigned short* aob = AO + (size_t)(b * 4096 + n) * 128 + (h << 5);
#pragma unroll
  for (int dt = 0; dt < 2; ++dt) {
    f32x4 o = opv[dt] * inv;
    ushort4v u = {f2bf(o[0]), f2bf(o[1]), f2bf(o[2]), f2bf(o[3])};
    *(ushort4v*)&aob[(dt << 4) + (g << 2)] = u;
  }
}

// ---------------------------------------------------------------------------
// Fused proj + residual + LN2.
// Block: 64 positions x all 128 channels (grid 256, 4 waves).
// X1 = x + AO.Wp + bp (f32 NCHW write); LN over channels in-register
// (channels live in 16 l15-lanes x 8 regs -> 8 adds + 4 shfl_xor w16);
// XLN2 [B*N,128] bf16 written directly. Kills ln2 launch + X1 re-read.
// ---------------------------------------------------------------------------
__global__ __launch_bounds__(256) void proj_ln2_kernel(
    const unsigned short* __restrict__ AO,   // [16384,128] bf16
    const unsigned short* __restrict__ Wp,   // [128,128] bf16
    const float* __restrict__ bp,
    const float* __restrict__ x,             // NCHW f32
    const float* __restrict__ g2,
    const float* __restrict__ b2,
    float* __restrict__ X1,                  // NCHW f32
    unsigned short* __restrict__ XLN2) {     // [16384,128] bf16
  __shared__ __align__(16) unsigned short As[64][128];
  __shared__ __align__(16) unsigned short Ws[128][128];
  const int t = threadIdx.x;
  const int w = t >> 6, lane = t & 63;
  const int l15 = lane & 15, g = lane >> 4;
  const int srow = t >> 4, schunk = t & 15;
  const int row0 = blockIdx.x << 6;          // 256 blocks x 64 positions
#pragma unroll
  for (int i = 0; i < 4; ++i) {              // A tile 64x128
    int row = i * 16 + srow;
    int c = schunk ^ (row & 7);
    *(ushort8*)&As[row][c * 8] =
        *(const ushort8*)&AO[(size_t)(row0 + row) * 128 + schunk * 8];
  }
#pragma unroll
  for (int i = 0; i < 8; ++i) {              // W 128x128 (entire proj_w)
    int row = i * 16 + srow;
    int c = schunk ^ (row & 7);
    *(ushort8*)&Ws[row][c * 8] =
        *(const ushort8*)&Wp[(size_t)row * 128 + schunk * 8];
  }
  __syncthreads();
  f32x4 acc[8];
#pragma unroll
  for (int nj = 0; nj < 8; ++nj) acc[nj] = (f32x4){0.f, 0.f, 0.f, 0.f};
#pragma unroll
  for (int kk = 0; kk < 4; ++kk) {
    int mrow = (w << 4) + l15;
    int ca = (kk * 4 + g) ^ (mrow & 7);
    bf16x8 aA = *(const bf16x8*)&As[mrow][ca * 8];
#pragma unroll
    for (int nj = 0; nj < 8; ++nj) {
      int wrow = (nj << 4) + l15;
      int cw = (kk * 4 + g) ^ (wrow & 7);
      bf16x8 bW = *(const bf16x8*)&Ws[wrow][cw * 8];
      acc[nj] = __builtin_amdgcn_mfma_f32_16x16x32_bf16(aA, bW, acc[nj], 0, 0, 0);
    }
  }
  // epilogue: residual, X1 write, in-register LN over channels, XLN2 write
  const int grow = row0 + (w << 4) + (g << 2);   // 4 positions (r=0..3)
  const int b = grow >> 12, n0 = grow & 4095;
  f32x4 val[8];
  f32x4 s = {0.f, 0.f, 0.f, 0.f}, ss = {0.f, 0.f, 0.f, 0.f};
#pragma unroll
  for (int nj = 0; nj < 8; ++nj) {
    int c = (nj << 4) + l15;
    size_t idx = ((size_t)(b * C_ + c) << 12) + n0;
    f32x4 xv = *(const f32x4*)&x[idx];
    val[nj] = xv + acc[nj] + bp[c];
    *(f32x4*)&X1[idx] = val[nj];
    s += val[nj];
    ss += val[nj] * val[nj];
  }
#pragma unroll
  for (int m = 1; m < 16; m <<= 1) {
    f32x4 so, sso;
#pragma unroll
    for (int r = 0; r < 4; ++r) {
      so[r] = __shfl_xor(s[r], m, 16);
      sso[r] = __shfl_xor(ss[r], m, 16);
    }
    s += so;
    ss += sso;
  }
  f32x4 mu = s * (1.f / 128.f);
  f32x4 rs;
#pragma unroll
  for (int r = 0; r < 4; ++r) {
    float var = ss[r] * (1.f / 128.f) - mu[r] * mu[r];
    rs[r] = rsqrtf(var + 1e-5f);
  }
  unsigned short* ob = XLN2 + (size_t)grow * C_;
#pragma unroll
  for (int nj = 0; nj < 8; ++nj) {
    int c = (nj << 4) + l15;
    float gam = g2[c], bet = b2[c];
#pragma unroll
    for (int r = 0; r < 4; ++r) {
      float v = (val[nj][r] - mu[r]) * rs[r] * gam + bet;
      ob[(size_t)r * C_ + c] = f2bf(v);
    }
  }
}

// fc1 + exact GELU -> H bf16 [16384, 256]
__global__ __launch_bounds__(256) void fc1_kernel(const unsigned short* __restrict__ XLN2,
                                                  const unsigned short* __restrict__ W1,
                                                  const float* __restrict__ b1,
                                                  unsigned short* __restrict__ Hb) {
  const int row0 = blockIdx.x << 7, col0 = blockIdx.y << 6;
  f32x4 acc[2][4] = {};
  mfma_core<128>(XLN2, W1, row0, col0, acc);
  const int t = threadIdx.x, w = t >> 6, lane = t & 63;
  const int l15 = lane & 15, g = lane >> 4;
#pragma unroll
  for (int mi = 0; mi < 2; ++mi) {
    int grow = row0 + (w << 5) + (mi << 4) + (g << 2);
#pragma unroll
    for (int nj = 0; nj < 4; ++nj) {
      int o = col0 + (nj << 4) + l15;
      float bb = b1[o];
#pragma unroll
      for (int r = 0; r < 4; ++r) {
        float v = acc[mi][nj][r] + bb;
        v = 0.5f * v * (1.f + erff(v * 0.70710678118654752f));
        Hb[(size_t)(grow + r) * 256 + o] = f2bf(v);
      }
    }
  }
}

// fc2 + residual -> out f32 NCHW
__global__ __launch_bounds__(256) void fc2_kernel(const unsigned short* __restrict__ Hb,
                                                  const unsigned short* __restrict__ W2,
                                                  const float* __restrict__ b2,
                                                  const float* __restrict__ X1,
                                                  float* __restrict__ outp) {
  const int row0 = blockIdx.x << 7, col0 = blockIdx.y << 6;
  f32x4 acc[2][4] = {};
  mfma_core<256>(Hb, W2, row0, col0, acc);
  const int t = threadIdx.x, w = t >> 6, lane = t & 63;
  const int l15 = lane & 15, g = lane >> 4;
#pragma unroll
  for (int mi = 0; mi < 2; ++mi) {
    int grow = row0 + (w << 5) + (mi << 4) + (g << 2);
    int b = grow >> 12, n0 = grow & 4095;
#pragma unroll
    for (int nj = 0; nj < 4; ++nj) {
      int c = col0 + (nj << 4) + l15;
      size_t idx = ((size_t)(b * C_ + c) << 12) + n0;
      f32x4 xv = *(const f32x4*)&X1[idx];
      f32x4 r = xv + acc[mi][nj] + b2[c];
      *(f32x4*)&outp[idx] = r;
    }
  }
}

extern "C" void kernel_launch(void* const* d_in, const int* in_sizes, int n_in,
                              void* d_out, int out_size, void* d_ws, size_t ws_size,
                              hipStream_t stream) {
  (void)in_sizes; (void)n_in; (void)out_size; (void)ws_size;
  const float* x     = (const float*)d_in[0];
  const float* ln1w  = (const float*)d_in[1];
  const float* ln1b  = (const float*)d_in[2];
  const float* qkvw  = (const float*)d_in[3];
  const float* projw = (const float*)d_in[4];
  const float* projb = (const float*)d_in[5];
  const float* ln2w  = (const float*)d_in[6];
  const float* ln2b  = (const float*)d_in[7];
  const float* fc1w  = (const float*)d_in[8];
  const float* fc1b  = (const float*)d_in[9];
  const float* fc2w  = (const float*)d_in[10];
  const float* fc2b  = (const float*)d_in[11];
  float* out = (float*)d_out;
  char* ws8 = (char*)d_ws;

  const size_t MB = 1u << 20;
  unsigned short* WB   = (unsigned short*)(ws8);            // 256 KB used
  unsigned short* XLN  = (unsigned short*)(ws8 + 1 * MB);   // 4 MB, reused as AO
  unsigned short* Qb   = (unsigned short*)(ws8 + 5 * MB);   // 4 MB, reused as XLN2
  unsigned short* Kb   = (unsigned short*)(ws8 + 9 * MB);   // 4 MB
  unsigned short* Vb   = (unsigned short*)(ws8 + 13 * MB);  // 4 MB
  unsigned short* AObf = XLN;                               // after qkv
  unsigned short* XLN2 = Qb;                                // after attn
  unsigned short* HB   = Kb;                                // 8 MB (K+V), after attn
  float*          X1   = (float*)(ws8 + 17 * MB);           // 8 MB
  const unsigned short* Wqkv = WB;
  const unsigned short* Wproj = WB + 49152;
  const unsigned short* Wfc1 = WB + 65536;
  const unsigned short* Wfc2 = WB + 98304;

  wconv_kernel<<<dim3(512), dim3(256), 0, stream>>>(qkvw, projw, fc1w, fc2w, WB);
  ln_kernel<<<dim3(512), dim3(256), 0, stream>>>(x, ln1w, ln1b, XLN);
  qkv_kernel<<<dim3(128, 6), dim3(256), 0, stream>>>(XLN, Wqkv, Qb, Kb, Vb);
  attn_kernel<<<dim3(1024), dim3(256), 0, stream>>>(Qb, Kb, Vb, AObf);
  proj_ln2_kernel<<<dim3(256), dim3(256), 0, stream>>>(AObf, Wproj, projb, x,
                                                       ln2w, ln2b, X1, XLN2);
  fc1_kernel<<<dim3(128, 4), dim3(256), 0, stream>>>(XLN2, Wfc1, fc1b, HB);
  fc2_kernel<<<dim3(128, 2), dim3(256), 0, stream>>>(HB, Wfc2, fc2b, X1, out);
}